// Round 10
// baseline (203.460 us; speedup 1.0000x reference)
//
#include <hip/hip_runtime.h>

#define DEVI __device__ __forceinline__

typedef __attribute__((ext_vector_type(8)))  short s16x8;
typedef __attribute__((ext_vector_type(4)))  short s16x4;
typedef __attribute__((ext_vector_type(4)))  float f32x4;
typedef __attribute__((ext_vector_type(16))) float f32x16;
typedef __attribute__((ext_vector_type(2)))  unsigned u32x2;
typedef __attribute__((ext_vector_type(4)))  unsigned u32x4;

// float -> bf16 (RNE), bit pattern as short
DEVI short f2bf(float f) {
  unsigned u = __builtin_bit_cast(unsigned, f);
  u = u + 0x7fffu + ((u >> 16) & 1u);
  return (short)(u >> 16);
}
// two floats -> packed bf16 pair via HW cvt (RNE)
DEVI unsigned cvtpk(float lo, float hi) {
  unsigned r;
  asm("v_cvt_pk_bf16_f32 %0, %1, %2" : "=v"(r) : "v"(lo), "v"(hi));
  return r;
}
// opaque zero: compiler cannot prove it's 0 -> defeats cross-rep CSE/hoist
DEVI int opaque_zero() {
  int z = 0;
  asm volatile("" : "+v"(z));
  return z;
}

constexpr int TT = 512;
constexpr int CC = 64;
constexpr float SCLQ = 0.18033688011112042f;  // log2(e)/8, folded into Q

// DIAGNOSTIC DILATION (this round only): repeat full work in-kernel so the
// dispatches exceed the rocprof top-5 cutoff (~42us) and get counters.
constexpr int QKV_REPS = 8;
constexpr int ATTN_REPS = 4;

// ---------------------------------------------------------------------------
// Kernel 0: weight repack fp32 -> bf16.  WqB[kk][co][ci] = Wq[co][ci][kk]
// ---------------------------------------------------------------------------
__global__ __launch_bounds__(256) void k_prep(const float* __restrict__ Wq,
                                              const float* __restrict__ Wk,
                                              const float* __restrict__ Wv,
                                              const float* __restrict__ Wf,
                                              short* __restrict__ wsw) {
  int i = blockIdx.x * 256 + threadIdx.x;
  const int total = 12288 + 12288 + 4096 + 4096;
  if (i >= total) return;
  if (i < 12288) {
    int kk = i >> 12, rem = i & 4095;
    wsw[(kk << 12) + rem] = f2bf(Wq[rem * 3 + kk]);
  } else if (i < 24576) {
    int j = i - 12288;
    int kk = j >> 12, rem = j & 4095;
    wsw[12288 + (kk << 12) + rem] = f2bf(Wk[rem * 3 + kk]);
  } else if (i < 28672) {
    int j = i - 24576;
    wsw[24576 + j] = f2bf(Wv[j]);
  } else {
    int j = i - 28672;
    wsw[28672 + j] = f2bf(Wf[j]);
  }
}

// ---------------------------------------------------------------------------
// Kernel 1: Q/K causal conv (3 shifted GEMMs) + V 1x1 conv via
// mfma_f32_32x32x16_bf16.  Q pre-scaled by log2(e)/8.  V written transposed
// vgT[bn][c][t] via LDS transpose.  DILATED x QKV_REPS (idempotent reps).
// ---------------------------------------------------------------------------
__global__ __launch_bounds__(256) void k_qkv(const float* __restrict__ values,
                                             const float* __restrict__ keys,
                                             const float* __restrict__ query,
                                             const float* __restrict__ bq,
                                             const float* __restrict__ bk,
                                             const short* __restrict__ wsw,
                                             short* __restrict__ qg,
                                             short* __restrict__ kg,
                                             short* __restrict__ vgT) {
  __shared__ __align__(16) short lq[130 * 64];
  __shared__ __align__(16) short lk[130 * 64];
  __shared__ __align__(16) short lv[128 * 64];
  __shared__ __align__(16) short lvT[64 * 128];  // [co][t_local], XOR swizzled
  const int tid = threadIdx.x;
  const int bn = blockIdx.x >> 2, ttile = blockIdx.x & 3;
  const int t0 = ttile * 128;
  const size_t xbase = (size_t)bn * TT * CC;
  const int lane = tid & 63, w = tid >> 6;
  const int r = lane & 31, hl = lane >> 5;

  for (int rep = 0; rep < QKV_REPS; ++rep) {
    int roff = opaque_zero();
    const float* valp = values + roff;
    const float* keyp = keys + roff;
    const float* qryp = query + roff;
    const short* wswp = wsw + roff;

    // stage query/keys rows [t0-2, t0+128)  (zeros for t<0)
    for (int s = tid; s < 130 * 8; s += 256) {
      int row = s >> 3, c8 = s & 7;
      int t = t0 - 2 + row;
      u32x4 rq, rk;
      if (t >= 0) {
        const float4 qa = *(const float4*)(qryp + xbase + (size_t)t * 64 + c8 * 8);
        const float4 qb = *(const float4*)(qryp + xbase + (size_t)t * 64 + c8 * 8 + 4);
        const float4 ka = *(const float4*)(keyp + xbase + (size_t)t * 64 + c8 * 8);
        const float4 kb = *(const float4*)(keyp + xbase + (size_t)t * 64 + c8 * 8 + 4);
        rq[0] = cvtpk(qa.x, qa.y); rq[1] = cvtpk(qa.z, qa.w);
        rq[2] = cvtpk(qb.x, qb.y); rq[3] = cvtpk(qb.z, qb.w);
        rk[0] = cvtpk(ka.x, ka.y); rk[1] = cvtpk(ka.z, ka.w);
        rk[2] = cvtpk(kb.x, kb.y); rk[3] = cvtpk(kb.z, kb.w);
      } else {
        rq = (u32x4)(0u); rk = (u32x4)(0u);
      }
      int byte = row * 128 + ((c8 * 16) ^ ((row & 7) << 4));
      *(u32x4*)((char*)lq + byte) = rq;
      *(u32x4*)((char*)lk + byte) = rk;
    }
    // stage values rows [t0, t0+128)
    for (int s = tid; s < 128 * 8; s += 256) {
      int row = s >> 3, c8 = s & 7;
      const float4 va = *(const float4*)(valp + xbase + (size_t)(t0 + row) * 64 + c8 * 8);
      const float4 vb = *(const float4*)(valp + xbase + (size_t)(t0 + row) * 64 + c8 * 8 + 4);
      u32x4 rv;
      rv[0] = cvtpk(va.x, va.y); rv[1] = cvtpk(va.z, va.w);
      rv[2] = cvtpk(vb.x, vb.y); rv[3] = cvtpk(vb.z, vb.w);
      int byte = row * 128 + ((c8 * 16) ^ ((row & 7) << 4));
      *(u32x4*)((char*)lv + byte) = rv;
    }
    __syncthreads();

    const short* wqb = wswp;            // [3][64][64]
    const short* wkb = wswp + 12288;    // [3][64][64]
    const short* wvb = wswp + 24576;    // [64][64]

    // 24 tiles: tensor(3: Q,K,V) x mt(4) x nt(2); wave-strided
    for (int job = w; job < 24; job += 4) {
      int tsr = job >> 3, tj = job & 7, mt = tj >> 1, nt = tj & 1;
      f32x16 acc;
#pragma unroll
      for (int i = 0; i < 16; ++i) acc[i] = 0.f;

      if (tsr < 2) {
        const short* lsrc = tsr ? lk : lq;
        const short* wb = tsr ? wkb : wqb;
#pragma unroll
        for (int kk = 0; kk < 3; ++kk) {
#pragma unroll
          for (int c4 = 0; c4 < 4; ++c4) {
            int lrow = mt * 32 + r + kk;
            int abyte = lrow * 128 + (((c4 * 16 + hl * 8) * 2) ^ ((lrow & 7) << 4));
            s16x8 af = *(const s16x8*)((const char*)lsrc + abyte);
            s16x8 bfr = *(const s16x8*)(wb + kk * 4096 + (nt * 32 + r) * 64 + c4 * 16 + hl * 8);
            acc = __builtin_amdgcn_mfma_f32_32x32x16_bf16(af, bfr, acc, 0, 0, 0);
          }
        }
      } else {
#pragma unroll
        for (int c4 = 0; c4 < 4; ++c4) {
          int lrow = mt * 32 + r;
          int abyte = lrow * 128 + (((c4 * 16 + hl * 8) * 2) ^ ((lrow & 7) << 4));
          s16x8 af = *(const s16x8*)((const char*)lv + abyte);
          s16x8 bfr = *(const s16x8*)(wvb + (nt * 32 + r) * 64 + c4 * 16 + hl * 8);
          acc = __builtin_amdgcn_mfma_f32_32x32x16_bf16(af, bfr, acc, 0, 0, 0);
        }
      }
      int co = nt * 32 + r;
      if (tsr == 2) {
#pragma unroll
        for (int g2 = 0; g2 < 4; ++g2) {
          int tl = mt * 32 + g2 * 8 + hl * 4;
          u32x2 pk;
          pk[0] = cvtpk(acc[g2 * 4 + 0], acc[g2 * 4 + 1]);
          pk[1] = cvtpk(acc[g2 * 4 + 2], acc[g2 * 4 + 3]);
          *(u32x2*)(lvT + co * 128 + (tl ^ ((co & 15) << 2))) = pk;
        }
      } else {
        float bias = tsr ? bk[co] : bq[co];
        float scl = tsr ? 1.f : SCLQ;
        short* dst = tsr ? kg : qg;
#pragma unroll
        for (int reg = 0; reg < 16; ++reg) {
          int trow = mt * 32 + (reg & 3) + 8 * (reg >> 2) + 4 * hl;
          dst[((size_t)bn * TT + (t0 + trow)) * 64 + co] = f2bf((acc[reg] + bias) * scl);
        }
      }
    }
    __syncthreads();
    // coalesced copy-out: vgT[bn][co][t0 + t]
#pragma unroll
    for (int i = 0; i < 8; ++i) {
      int chunk = tid + 256 * i;          // 2048 chunks of 4 shorts
      int co = chunk >> 5, tc = chunk & 31;
      s16x4 v4 = *(const s16x4*)(lvT + co * 128 + ((tc * 4) ^ ((co & 15) << 2)));
      *(s16x4*)(vgT + ((size_t)bn * 64 + co) * TT + t0 + tc * 4) = v4;
    }
  }
}

// ---------------------------------------------------------------------------
// Kernel 2: attention (round-9 structure, proven).  Grid 1024 = (bn,h,qq);
// 4 waves, 1 mt/wave.  One-pass no-max softmax; native exp2 shielded by
// v_max; P in registers via cvt_pk + v_permlane32_swap_b32.
// DILATED x ATTN_REPS (idempotent reps; K staged once).
// ---------------------------------------------------------------------------
__global__ __launch_bounds__(256, 4) void k_attn(const short* __restrict__ qg,
                                                 const short* __restrict__ kg,
                                                 const short* __restrict__ vgT,
                                                 short* __restrict__ ag) {
  __shared__ __align__(16) short Kl[512 * 16];   // frag-major: tile nt at nt*512, lane*8
  __shared__ float Sums[4][32];
  const int tid = threadIdx.x;
  // bijective XCD swizzle: all 16 (h,qq) blocks of one bn land on one XCD
  const int b = (blockIdx.x & 7) * 128 + (blockIdx.x >> 3);
  const int bn = b >> 4, h = (b >> 2) & 3, qq = b & 3;
  const int lane = tid & 63, w = tid >> 6;
  const int r = lane & 31, hl = lane >> 5;

  // stage K slice (512 x 16) into fragment-major LDS
  const short* kslice = kg + (size_t)bn * TT * CC + h * 16;
  for (int s = tid; s < 1024; s += 256) {
    int row = s >> 1, hh = s & 1;
    s16x8 kv = *(const s16x8*)(kslice + (size_t)row * CC + hh * 8);
    *(s16x8*)(Kl + (row >> 5) * 512 + (row & 31) * 8 + hh * 256) = kv;
  }
  __syncthreads();

  const int mt = qq * 4 + w;
  const short* vb0 = vgT + ((size_t)bn * 64 + h * 16 + (r & 15)) * TT;

  for (int rep = 0; rep < ATTN_REPS; ++rep) {
    int roff = opaque_zero();
    s16x8 qf = *(const s16x8*)(qg + ((size_t)bn * TT + mt * 32 + r) * CC + h * 16 + hl * 8 + roff);
    const short* vb = vb0 + roff;
    const short* klp = Kl + roff;

    f32x16 z;
#pragma unroll
    for (int i = 0; i < 16; ++i) z[i] = 0.f;
    float sm0 = 0.f, sm1 = 0.f, sm2 = 0.f, sm3 = 0.f;
    f32x16 o;
#pragma unroll
    for (int i = 0; i < 16; ++i) o[i] = 0.f;

#pragma unroll
    for (int nt = 0; nt < 16; ++nt) {
      s16x8 kf = *(const s16x8*)(klp + nt * 512 + lane * 8);
      f32x16 s = __builtin_amdgcn_mfma_f32_32x32x16_bf16(kf, qf, z, 0, 0, 0);
      float p[16];
#pragma unroll
      for (int i = 0; i < 16; ++i)
        p[i] = fmaxf(__builtin_amdgcn_exp2f(s[i]), 0.f);  // v_max shields asm consumer
#pragma unroll
      for (int i = 0; i < 4; ++i) {
        sm0 += p[4 * i + 0]; sm1 += p[4 * i + 1];
        sm2 += p[4 * i + 2]; sm3 += p[4 * i + 3];
      }
      unsigned pk[8];
#pragma unroll
      for (int m = 0; m < 8; ++m) pk[m] = cvtpk(p[2 * m], p[2 * m + 1]);
#pragma unroll
      for (int s2 = 0; s2 < 2; ++s2) {
        unsigned a0 = pk[4 * s2 + 0], b0 = pk[4 * s2 + 2];
        unsigned a1 = pk[4 * s2 + 1], b1 = pk[4 * s2 + 3];
        asm("v_permlane32_swap_b32 %0, %1" : "+v"(a0), "+v"(b0));
        asm("v_permlane32_swap_b32 %0, %1" : "+v"(a1), "+v"(b1));
        u32x4 fw; fw[0] = a0; fw[1] = a1; fw[2] = b0; fw[3] = b1;
        s16x8 fr = __builtin_bit_cast(s16x8, fw);
        s16x8 vf = *(const s16x8*)(vb + nt * 32 + s2 * 16 + hl * 8);
        o = __builtin_amdgcn_mfma_f32_32x32x16_bf16(fr, vf, o, 0, 0, 0);
      }
    }
    float sum = (sm0 + sm1) + (sm2 + sm3);
    sum += __shfl_xor(sum, 32);
    Sums[w][r] = sum;
    if (r < 16) {
#pragma unroll
      for (int reg = 0; reg < 16; ++reg) {
        int qlocal = (reg & 3) + 8 * (reg >> 2) + 4 * hl;
        float inv = __builtin_amdgcn_rcpf(Sums[w][qlocal]);
        int q = mt * 32 + qlocal;
        ag[((size_t)bn * TT + q) * CC + h * 16 + r] = f2bf(o[reg] * inv);
      }
    }
  }
}

// ---------------------------------------------------------------------------
// Kernel 3: final linear out = attn @ Wf^T + bf (fp32 out)
// ---------------------------------------------------------------------------
__global__ __launch_bounds__(256) void k_out(const short* __restrict__ ag,
                                             const short* __restrict__ wfb,
                                             const float* __restrict__ bfv,
                                             float* __restrict__ out) {
  __shared__ __align__(16) short la[128 * 64];
  const int tid = threadIdx.x;
  const int bn = blockIdx.x >> 2, ttile = blockIdx.x & 3;
  const int t0 = ttile * 128;
  for (int s = tid; s < 128 * 8; s += 256) {
    int row = s >> 3, c8 = s & 7;
    s16x8 v = *(const s16x8*)(ag + ((size_t)bn * TT + t0 + row) * 64 + c8 * 8);
    int byte = row * 128 + ((c8 * 16) ^ ((row & 7) << 4));
    *(s16x8*)((char*)la + byte) = v;
  }
  __syncthreads();
  const int lane = tid & 63, w = tid >> 6;
  const int r = lane & 31, hl = lane >> 5;
  for (int job = w; job < 8; job += 4) {
    int mt = job >> 1, nt = job & 1;
    f32x16 acc;
#pragma unroll
    for (int i = 0; i < 16; ++i) acc[i] = 0.f;
#pragma unroll
    for (int c4 = 0; c4 < 4; ++c4) {
      int lrow = mt * 32 + r;
      int abyte = lrow * 128 + (((c4 * 16 + hl * 8) * 2) ^ ((lrow & 7) << 4));
      s16x8 af = *(const s16x8*)((const char*)la + abyte);
      s16x8 bfr = *(const s16x8*)(wfb + (nt * 32 + r) * 64 + c4 * 16 + hl * 8);
      acc = __builtin_amdgcn_mfma_f32_32x32x16_bf16(af, bfr, acc, 0, 0, 0);
    }
    int co = nt * 32 + r;
    float bias = bfv[co];
#pragma unroll
    for (int reg = 0; reg < 16; ++reg) {
      int trow = mt * 32 + (reg & 3) + 8 * (reg >> 2) + 4 * hl;
      out[((size_t)bn * TT + t0 + trow) * 64 + co] = acc[reg] + bias;
    }
  }
}

// ---------------------------------------------------------------------------
extern "C" void kernel_launch(void* const* d_in, const int* in_sizes, int n_in,
                              void* d_out, int out_size, void* d_ws, size_t ws_size,
                              hipStream_t stream) {
  const float* values = (const float*)d_in[0];
  const float* keys = (const float*)d_in[1];
  const float* query = (const float*)d_in[2];
  const float* Wq = (const float*)d_in[3];
  const float* bq = (const float*)d_in[4];
  const float* Wk = (const float*)d_in[5];
  const float* bk = (const float*)d_in[6];
  const float* Wv = (const float*)d_in[7];
  const float* Wf = (const float*)d_in[8];
  const float* bfv = (const float*)d_in[9];
  float* out = (float*)d_out;

  char* ws = (char*)d_ws;
  short* wsw = (short*)ws;                              // 64 KiB weights
  short* qg = (short*)(ws + (1 << 16));                 // 4 MiB each
  short* kg = (short*)(ws + (1 << 16) + (1 << 22));
  short* vgT = (short*)(ws + (1 << 16) + 2 * (1 << 22));
  short* ag = (short*)(ws + (1 << 16) + 3 * (size_t)(1 << 22));

  hipLaunchKernelGGL(k_prep, dim3(128), dim3(256), 0, stream, Wq, Wk, Wv, Wf, wsw);
  hipLaunchKernelGGL(k_qkv, dim3(256), dim3(256), 0, stream,
                     values, keys, query, bq, bk, wsw, qg, kg, vgT);
  hipLaunchKernelGGL(k_attn, dim3(1024), dim3(256), 0, stream, qg, kg, vgT, ag);
  hipLaunchKernelGGL(k_out, dim3(256), dim3(256), 0, stream, ag, wsw + 28672, bfv, out);
}

// Round 11
// 100.990 us; speedup vs baseline: 2.0146x; 2.0146x over previous
//
#include <hip/hip_runtime.h>

#define DEVI __device__ __forceinline__

typedef __attribute__((ext_vector_type(8)))  short s16x8;
typedef __attribute__((ext_vector_type(4)))  short s16x4;
typedef __attribute__((ext_vector_type(4)))  float f32x4;
typedef __attribute__((ext_vector_type(16))) float f32x16;
typedef __attribute__((ext_vector_type(2)))  unsigned u32x2;
typedef __attribute__((ext_vector_type(4)))  unsigned u32x4;

// float -> bf16 (RNE), bit pattern as short
DEVI short f2bf(float f) {
  unsigned u = __builtin_bit_cast(unsigned, f);
  u = u + 0x7fffu + ((u >> 16) & 1u);
  return (short)(u >> 16);
}
// two floats -> packed bf16 pair via HW cvt (RNE)
DEVI unsigned cvtpk(float lo, float hi) {
  unsigned r;
  asm("v_cvt_pk_bf16_f32 %0, %1, %2" : "=v"(r) : "v"(lo), "v"(hi));
  return r;
}
// opaque zero: compiler cannot prove it's 0 -> defeats cross-rep CSE/hoist
DEVI int opaque_zero() {
  int z = 0;
  asm volatile("" : "+v"(z));
  return z;
}

constexpr int TT = 512;
constexpr int CC = 64;
constexpr float SCLQ = 0.18033688011112042f;  // log2(e)/8, folded into Q

// DIAGNOSTIC (this round): k_attn dilated x4 to surface in rocprof top-5.
constexpr int ATTN_REPS = 4;

// ---------------------------------------------------------------------------
// Kernel 0: weight repack fp32 -> bf16.  WqB[kk][co][ci] = Wq[co][ci][kk]
// ---------------------------------------------------------------------------
__global__ __launch_bounds__(256) void k_prep(const float* __restrict__ Wq,
                                              const float* __restrict__ Wk,
                                              const float* __restrict__ Wv,
                                              const float* __restrict__ Wf,
                                              short* __restrict__ wsw) {
  int i = blockIdx.x * 256 + threadIdx.x;
  const int total = 12288 + 12288 + 4096 + 4096;
  if (i >= total) return;
  if (i < 12288) {
    int kk = i >> 12, rem = i & 4095;
    wsw[(kk << 12) + rem] = f2bf(Wq[rem * 3 + kk]);
  } else if (i < 24576) {
    int j = i - 12288;
    int kk = j >> 12, rem = j & 4095;
    wsw[12288 + (kk << 12) + rem] = f2bf(Wk[rem * 3 + kk]);
  } else if (i < 28672) {
    int j = i - 24576;
    wsw[24576 + j] = f2bf(Wv[j]);
  } else {
    int j = i - 28672;
    wsw[28672 + j] = f2bf(Wf[j]);
  }
}

// ---------------------------------------------------------------------------
// Kernel 1: QKV projections, OCCUPANCY-FIXED: grid 1536 = tensor(3) x bn(64)
// x t-tile(8 of 64 rows).  Each block stages only its own input slice
// (66-row halo for Q/K), 4 waves, 1 MFMA-job(32x64 out)/wave.
// r10 counters for the old 256-block version: Occupancy 11%, BW 1.58 TB/s,
// all pipes <10% -> grid-starved.  6 blocks/CU now.
// ---------------------------------------------------------------------------
__global__ __launch_bounds__(256) void k_qkv(const float* __restrict__ values,
                                             const float* __restrict__ keys,
                                             const float* __restrict__ query,
                                             const float* __restrict__ bq,
                                             const float* __restrict__ bk,
                                             const short* __restrict__ wsw,
                                             short* __restrict__ qg,
                                             short* __restrict__ kg,
                                             short* __restrict__ vgT) {
  __shared__ __align__(16) short lx[66 * 64];   // input tile (66 rows w/ halo)
  __shared__ __align__(16) short lxT[64 * 64];  // V transpose tile [co][t]
  const int idx = blockIdx.x;
  const int tsr = idx >> 9;                 // 0=Q 1=K 2=V
  const int sub = idx & 511;
  const int bn = sub >> 3, t8 = sub & 7;
  const int t0 = t8 * 64;
  const size_t xbase = (size_t)bn * TT * CC;
  const int tid = threadIdx.x;
  const int lane = tid & 63, w = tid >> 6;
  const int r = lane & 31, hl = lane >> 5;

  const float* in = (tsr == 0) ? query : (tsr == 1) ? keys : values;
  const int nrows = (tsr < 2) ? 66 : 64;
  const int halo = (tsr < 2) ? 2 : 0;

  // stage input rows [t0-halo, t0+64) as bf16, XOR-swizzled 128B rows
  for (int s = tid; s < nrows * 8; s += 256) {
    int row = s >> 3, c8 = s & 7;
    int t = t0 - halo + row;
    u32x4 rv;
    if (t >= 0) {
      const float4 a = *(const float4*)(in + xbase + (size_t)t * 64 + c8 * 8);
      const float4 b = *(const float4*)(in + xbase + (size_t)t * 64 + c8 * 8 + 4);
      rv[0] = cvtpk(a.x, a.y); rv[1] = cvtpk(a.z, a.w);
      rv[2] = cvtpk(b.x, b.y); rv[3] = cvtpk(b.z, b.w);
    } else {
      rv = (u32x4)(0u);
    }
    int byte = row * 128 + ((c8 * 16) ^ ((row & 7) << 4));
    *(u32x4*)((char*)lx + byte) = rv;
  }
  __syncthreads();

  // 4 jobs: mt(2) x nt(2); wave w takes job w
  {
    int mt = w >> 1, nt = w & 1;
    f32x16 acc;
#pragma unroll
    for (int i = 0; i < 16; ++i) acc[i] = 0.f;

    if (tsr < 2) {
      const short* wb = tsr ? (wsw + 12288) : wsw;   // [3][64][64]
#pragma unroll
      for (int kk = 0; kk < 3; ++kk) {
#pragma unroll
        for (int c4 = 0; c4 < 4; ++c4) {
          int lrow = mt * 32 + r + kk;
          int abyte = lrow * 128 + (((c4 * 16 + hl * 8) * 2) ^ ((lrow & 7) << 4));
          s16x8 af = *(const s16x8*)((const char*)lx + abyte);
          s16x8 bfr = *(const s16x8*)(wb + kk * 4096 + (nt * 32 + r) * 64 + c4 * 16 + hl * 8);
          acc = __builtin_amdgcn_mfma_f32_32x32x16_bf16(af, bfr, acc, 0, 0, 0);
        }
      }
    } else {
      const short* wvb = wsw + 24576;                // [64][64]
#pragma unroll
      for (int c4 = 0; c4 < 4; ++c4) {
        int lrow = mt * 32 + r;
        int abyte = lrow * 128 + (((c4 * 16 + hl * 8) * 2) ^ ((lrow & 7) << 4));
        s16x8 af = *(const s16x8*)((const char*)lx + abyte);
        s16x8 bfr = *(const s16x8*)(wvb + (nt * 32 + r) * 64 + c4 * 16 + hl * 8);
        acc = __builtin_amdgcn_mfma_f32_32x32x16_bf16(af, bfr, acc, 0, 0, 0);
      }
    }
    int co = nt * 32 + r;
    if (tsr == 2) {
      // write transposed to LDS: lxT[co][t_local], XOR-swizzled 4-chunks
#pragma unroll
      for (int g2 = 0; g2 < 4; ++g2) {
        int tl = mt * 32 + g2 * 8 + hl * 4;
        u32x2 pk;
        pk[0] = cvtpk(acc[g2 * 4 + 0], acc[g2 * 4 + 1]);
        pk[1] = cvtpk(acc[g2 * 4 + 2], acc[g2 * 4 + 3]);
        *(u32x2*)(lxT + co * 64 + (tl ^ ((co & 15) << 2))) = pk;
      }
    } else {
      float bias = tsr ? bk[co] : bq[co];
      float scl = tsr ? 1.f : SCLQ;
      short* dst = tsr ? kg : qg;
#pragma unroll
      for (int reg = 0; reg < 16; ++reg) {
        int trow = mt * 32 + (reg & 3) + 8 * (reg >> 2) + 4 * hl;
        dst[((size_t)bn * TT + (t0 + trow)) * 64 + co] = f2bf((acc[reg] + bias) * scl);
      }
    }
  }
  if (tsr == 2) {
    __syncthreads();
    // coalesced copy-out: vgT[bn][co][t0 + t], 1024 chunks of 4 shorts
#pragma unroll
    for (int i = 0; i < 4; ++i) {
      int chunk = tid + 256 * i;
      int co = chunk >> 4, tc = chunk & 15;
      s16x4 v4 = *(const s16x4*)(lxT + co * 64 + ((tc * 4) ^ ((co & 15) << 2)));
      *(s16x4*)(vgT + ((size_t)bn * 64 + co) * TT + t0 + tc * 4) = v4;
    }
  }
}

// ---------------------------------------------------------------------------
// Kernel 2: attention (r9 structure, proven).  Grid 1024 = (bn,h,qq);
// 4 waves, 1 mt/wave.  One-pass no-max softmax; native exp2 shielded by
// v_max; P in registers via cvt_pk + v_permlane32_swap_b32.
// DILATED x ATTN_REPS this round to surface counters in top-5.
// ---------------------------------------------------------------------------
__global__ __launch_bounds__(256, 4) void k_attn(const short* __restrict__ qg,
                                                 const short* __restrict__ kg,
                                                 const short* __restrict__ vgT,
                                                 short* __restrict__ ag) {
  __shared__ __align__(16) short Kl[512 * 16];   // frag-major: tile nt at nt*512, lane*8
  __shared__ float Sums[4][32];
  const int tid = threadIdx.x;
  // bijective XCD swizzle: all 16 (h,qq) blocks of one bn land on one XCD
  const int b = (blockIdx.x & 7) * 128 + (blockIdx.x >> 3);
  const int bn = b >> 4, h = (b >> 2) & 3, qq = b & 3;
  const int lane = tid & 63, w = tid >> 6;
  const int r = lane & 31, hl = lane >> 5;

  // stage K slice (512 x 16) into fragment-major LDS
  const short* kslice = kg + (size_t)bn * TT * CC + h * 16;
  for (int s = tid; s < 1024; s += 256) {
    int row = s >> 1, hh = s & 1;
    s16x8 kv = *(const s16x8*)(kslice + (size_t)row * CC + hh * 8);
    *(s16x8*)(Kl + (row >> 5) * 512 + (row & 31) * 8 + hh * 256) = kv;
  }
  __syncthreads();

  const int mt = qq * 4 + w;
  const short* vb0 = vgT + ((size_t)bn * 64 + h * 16 + (r & 15)) * TT;

  for (int rep = 0; rep < ATTN_REPS; ++rep) {
    int roff = opaque_zero();
    s16x8 qf = *(const s16x8*)(qg + ((size_t)bn * TT + mt * 32 + r) * CC + h * 16 + hl * 8 + roff);
    const short* vb = vb0 + roff;
    const short* klp = Kl + roff;

    f32x16 z;
#pragma unroll
    for (int i = 0; i < 16; ++i) z[i] = 0.f;
    float sm0 = 0.f, sm1 = 0.f, sm2 = 0.f, sm3 = 0.f;
    f32x16 o;
#pragma unroll
    for (int i = 0; i < 16; ++i) o[i] = 0.f;

#pragma unroll
    for (int nt = 0; nt < 16; ++nt) {
      s16x8 kf = *(const s16x8*)(klp + nt * 512 + lane * 8);
      f32x16 s = __builtin_amdgcn_mfma_f32_32x32x16_bf16(kf, qf, z, 0, 0, 0);
      float p[16];
#pragma unroll
      for (int i = 0; i < 16; ++i)
        p[i] = fmaxf(__builtin_amdgcn_exp2f(s[i]), 0.f);  // v_max shields asm consumer
#pragma unroll
      for (int i = 0; i < 4; ++i) {
        sm0 += p[4 * i + 0]; sm1 += p[4 * i + 1];
        sm2 += p[4 * i + 2]; sm3 += p[4 * i + 3];
      }
      unsigned pk[8];
#pragma unroll
      for (int m = 0; m < 8; ++m) pk[m] = cvtpk(p[2 * m], p[2 * m + 1]);
#pragma unroll
      for (int s2 = 0; s2 < 2; ++s2) {
        unsigned a0 = pk[4 * s2 + 0], b0 = pk[4 * s2 + 2];
        unsigned a1 = pk[4 * s2 + 1], b1 = pk[4 * s2 + 3];
        asm("v_permlane32_swap_b32 %0, %1" : "+v"(a0), "+v"(b0));
        asm("v_permlane32_swap_b32 %0, %1" : "+v"(a1), "+v"(b1));
        u32x4 fw; fw[0] = a0; fw[1] = a1; fw[2] = b0; fw[3] = b1;
        s16x8 fr = __builtin_bit_cast(s16x8, fw);
        s16x8 vf = *(const s16x8*)(vb + nt * 32 + s2 * 16 + hl * 8);
        o = __builtin_amdgcn_mfma_f32_32x32x16_bf16(fr, vf, o, 0, 0, 0);
      }
    }
    float sum = (sm0 + sm1) + (sm2 + sm3);
    sum += __shfl_xor(sum, 32);
    Sums[w][r] = sum;
    if (r < 16) {
#pragma unroll
      for (int reg = 0; reg < 16; ++reg) {
        int qlocal = (reg & 3) + 8 * (reg >> 2) + 4 * hl;
        float inv = __builtin_amdgcn_rcpf(Sums[w][qlocal]);
        int q = mt * 32 + qlocal;
        ag[((size_t)bn * TT + q) * CC + h * 16 + r] = f2bf(o[reg] * inv);
      }
    }
  }
}

// ---------------------------------------------------------------------------
// Kernel 3: final linear out = attn @ Wf^T + bf (fp32 out).
// OCCUPANCY-FIXED: grid 512 (64-row tiles), 1 job/wave.
// ---------------------------------------------------------------------------
__global__ __launch_bounds__(256) void k_out(const short* __restrict__ ag,
                                             const short* __restrict__ wfb,
                                             const float* __restrict__ bfv,
                                             float* __restrict__ out) {
  __shared__ __align__(16) short la[64 * 64];
  const int tid = threadIdx.x;
  const int bn = blockIdx.x >> 3, t8 = blockIdx.x & 7;
  const int t0 = t8 * 64;
  for (int s = tid; s < 64 * 8; s += 256) {
    int row = s >> 3, c8 = s & 7;
    s16x8 v = *(const s16x8*)(ag + ((size_t)bn * TT + t0 + row) * 64 + c8 * 8);
    int byte = row * 128 + ((c8 * 16) ^ ((row & 7) << 4));
    *(s16x8*)((char*)la + byte) = v;
  }
  __syncthreads();
  const int lane = tid & 63, w = tid >> 6;
  const int r = lane & 31, hl = lane >> 5;
  {
    int mt = w >> 1, nt = w & 1;
    f32x16 acc;
#pragma unroll
    for (int i = 0; i < 16; ++i) acc[i] = 0.f;
#pragma unroll
    for (int c4 = 0; c4 < 4; ++c4) {
      int lrow = mt * 32 + r;
      int abyte = lrow * 128 + (((c4 * 16 + hl * 8) * 2) ^ ((lrow & 7) << 4));
      s16x8 af = *(const s16x8*)((const char*)la + abyte);
      s16x8 bfr = *(const s16x8*)(wfb + (nt * 32 + r) * 64 + c4 * 16 + hl * 8);
      acc = __builtin_amdgcn_mfma_f32_32x32x16_bf16(af, bfr, acc, 0, 0, 0);
    }
    int co = nt * 32 + r;
    float bias = bfv[co];
#pragma unroll
    for (int reg = 0; reg < 16; ++reg) {
      int trow = mt * 32 + (reg & 3) + 8 * (reg >> 2) + 4 * hl;
      out[((size_t)bn * TT + t0 + trow) * 64 + co] = acc[reg] + bias;
    }
  }
}

// ---------------------------------------------------------------------------
extern "C" void kernel_launch(void* const* d_in, const int* in_sizes, int n_in,
                              void* d_out, int out_size, void* d_ws, size_t ws_size,
                              hipStream_t stream) {
  const float* values = (const float*)d_in[0];
  const float* keys = (const float*)d_in[1];
  const float* query = (const float*)d_in[2];
  const float* Wq = (const float*)d_in[3];
  const float* bq = (const float*)d_in[4];
  const float* Wk = (const float*)d_in[5];
  const float* bk = (const float*)d_in[6];
  const float* Wv = (const float*)d_in[7];
  const float* Wf = (const float*)d_in[8];
  const float* bfv = (const float*)d_in[9];
  float* out = (float*)d_out;

  char* ws = (char*)d_ws;
  short* wsw = (short*)ws;                              // 64 KiB weights
  short* qg = (short*)(ws + (1 << 16));                 // 4 MiB each
  short* kg = (short*)(ws + (1 << 16) + (1 << 22));
  short* vgT = (short*)(ws + (1 << 16) + 2 * (1 << 22));
  short* ag = (short*)(ws + (1 << 16) + 3 * (size_t)(1 << 22));

  hipLaunchKernelGGL(k_prep, dim3(128), dim3(256), 0, stream, Wq, Wk, Wv, Wf, wsw);
  hipLaunchKernelGGL(k_qkv, dim3(1536), dim3(256), 0, stream,
                     values, keys, query, bq, bk, wsw, qg, kg, vgT);
  hipLaunchKernelGGL(k_attn, dim3(1024), dim3(256), 0, stream, qg, kg, vgT, ag);
  hipLaunchKernelGGL(k_out, dim3(512), dim3(256), 0, stream, ag, wsw + 28672, bfv, out);
}

// Round 12
// 49.663 us; speedup vs baseline: 4.0968x; 2.0335x over previous
//
#include <hip/hip_runtime.h>

#define DEVI __device__ __forceinline__

typedef __attribute__((ext_vector_type(8)))  short s16x8;
typedef __attribute__((ext_vector_type(4)))  short s16x4;
typedef __attribute__((ext_vector_type(4)))  float f32x4;
typedef __attribute__((ext_vector_type(16))) float f32x16;
typedef __attribute__((ext_vector_type(2)))  unsigned u32x2;
typedef __attribute__((ext_vector_type(4)))  unsigned u32x4;

// float -> bf16 (RNE), bit pattern as short
DEVI short f2bf(float f) {
  unsigned u = __builtin_bit_cast(unsigned, f);
  u = u + 0x7fffu + ((u >> 16) & 1u);
  return (short)(u >> 16);
}
// two floats -> packed bf16 pair via HW cvt (RNE)
DEVI unsigned cvtpk(float lo, float hi) {
  unsigned r;
  asm("v_cvt_pk_bf16_f32 %0, %1, %2" : "=v"(r) : "v"(lo), "v"(hi));
  return r;
}

constexpr int TT = 512;
constexpr int CC = 64;
constexpr float SCLQ = 0.18033688011112042f;  // log2(e)/8, folded into Q

// ---------------------------------------------------------------------------
// Kernel 0: weight repack fp32 -> bf16.  WqB[kk][co][ci] = Wq[co][ci][kk]
// ---------------------------------------------------------------------------
__global__ __launch_bounds__(256) void k_prep(const float* __restrict__ Wq,
                                              const float* __restrict__ Wk,
                                              const float* __restrict__ Wv,
                                              const float* __restrict__ Wf,
                                              short* __restrict__ wsw) {
  int i = blockIdx.x * 256 + threadIdx.x;
  const int total = 12288 + 12288 + 4096 + 4096;
  if (i >= total) return;
  if (i < 12288) {
    int kk = i >> 12, rem = i & 4095;
    wsw[(kk << 12) + rem] = f2bf(Wq[rem * 3 + kk]);
  } else if (i < 24576) {
    int j = i - 12288;
    int kk = j >> 12, rem = j & 4095;
    wsw[12288 + (kk << 12) + rem] = f2bf(Wk[rem * 3 + kk]);
  } else if (i < 28672) {
    int j = i - 24576;
    wsw[24576 + j] = f2bf(Wv[j]);
  } else {
    int j = i - 28672;
    wsw[28672 + j] = f2bf(Wf[j]);
  }
}

// ---------------------------------------------------------------------------
// Kernel 1: QKV projections (r11 occupancy-fixed version, proven).
// Grid 1536 = tensor(3) x bn(64) x t-tile(8 of 64 rows).
// ---------------------------------------------------------------------------
__global__ __launch_bounds__(256) void k_qkv(const float* __restrict__ values,
                                             const float* __restrict__ keys,
                                             const float* __restrict__ query,
                                             const float* __restrict__ bq,
                                             const float* __restrict__ bk,
                                             const short* __restrict__ wsw,
                                             short* __restrict__ qg,
                                             short* __restrict__ kg,
                                             short* __restrict__ vgT) {
  __shared__ __align__(16) short lx[66 * 64];   // input tile (66 rows w/ halo)
  __shared__ __align__(16) short lxT[64 * 64];  // V transpose tile [co][t]
  const int idx = blockIdx.x;
  const int tsr = idx >> 9;                 // 0=Q 1=K 2=V
  const int sub = idx & 511;
  const int bn = sub >> 3, t8 = sub & 7;
  const int t0 = t8 * 64;
  const size_t xbase = (size_t)bn * TT * CC;
  const int tid = threadIdx.x;
  const int lane = tid & 63, w = tid >> 6;
  const int r = lane & 31, hl = lane >> 5;

  const float* in = (tsr == 0) ? query : (tsr == 1) ? keys : values;
  const int nrows = (tsr < 2) ? 66 : 64;
  const int halo = (tsr < 2) ? 2 : 0;

  // stage input rows [t0-halo, t0+64) as bf16, XOR-swizzled 128B rows
  for (int s = tid; s < nrows * 8; s += 256) {
    int row = s >> 3, c8 = s & 7;
    int t = t0 - halo + row;
    u32x4 rv;
    if (t >= 0) {
      const float4 a = *(const float4*)(in + xbase + (size_t)t * 64 + c8 * 8);
      const float4 b = *(const float4*)(in + xbase + (size_t)t * 64 + c8 * 8 + 4);
      rv[0] = cvtpk(a.x, a.y); rv[1] = cvtpk(a.z, a.w);
      rv[2] = cvtpk(b.x, b.y); rv[3] = cvtpk(b.z, b.w);
    } else {
      rv = (u32x4)(0u);
    }
    int byte = row * 128 + ((c8 * 16) ^ ((row & 7) << 4));
    *(u32x4*)((char*)lx + byte) = rv;
  }
  __syncthreads();

  // 4 jobs: mt(2) x nt(2); wave w takes job w
  {
    int mt = w >> 1, nt = w & 1;
    f32x16 acc;
#pragma unroll
    for (int i = 0; i < 16; ++i) acc[i] = 0.f;

    if (tsr < 2) {
      const short* wb = tsr ? (wsw + 12288) : wsw;   // [3][64][64]
#pragma unroll
      for (int kk = 0; kk < 3; ++kk) {
#pragma unroll
        for (int c4 = 0; c4 < 4; ++c4) {
          int lrow = mt * 32 + r + kk;
          int abyte = lrow * 128 + (((c4 * 16 + hl * 8) * 2) ^ ((lrow & 7) << 4));
          s16x8 af = *(const s16x8*)((const char*)lx + abyte);
          s16x8 bfr = *(const s16x8*)(wb + kk * 4096 + (nt * 32 + r) * 64 + c4 * 16 + hl * 8);
          acc = __builtin_amdgcn_mfma_f32_32x32x16_bf16(af, bfr, acc, 0, 0, 0);
        }
      }
    } else {
      const short* wvb = wsw + 24576;                // [64][64]
#pragma unroll
      for (int c4 = 0; c4 < 4; ++c4) {
        int lrow = mt * 32 + r;
        int abyte = lrow * 128 + (((c4 * 16 + hl * 8) * 2) ^ ((lrow & 7) << 4));
        s16x8 af = *(const s16x8*)((const char*)lx + abyte);
        s16x8 bfr = *(const s16x8*)(wvb + (nt * 32 + r) * 64 + c4 * 16 + hl * 8);
        acc = __builtin_amdgcn_mfma_f32_32x32x16_bf16(af, bfr, acc, 0, 0, 0);
      }
    }
    int co = nt * 32 + r;
    if (tsr == 2) {
      // write transposed to LDS: lxT[co][t_local], XOR-swizzled 4-chunks
#pragma unroll
      for (int g2 = 0; g2 < 4; ++g2) {
        int tl = mt * 32 + g2 * 8 + hl * 4;
        u32x2 pk;
        pk[0] = cvtpk(acc[g2 * 4 + 0], acc[g2 * 4 + 1]);
        pk[1] = cvtpk(acc[g2 * 4 + 2], acc[g2 * 4 + 3]);
        *(u32x2*)(lxT + co * 64 + (tl ^ ((co & 15) << 2))) = pk;
      }
    } else {
      float bias = tsr ? bk[co] : bq[co];
      float scl = tsr ? 1.f : SCLQ;
      short* dst = tsr ? kg : qg;
#pragma unroll
      for (int reg = 0; reg < 16; ++reg) {
        int trow = mt * 32 + (reg & 3) + 8 * (reg >> 2) + 4 * hl;
        dst[((size_t)bn * TT + (t0 + trow)) * 64 + co] = f2bf((acc[reg] + bias) * scl);
      }
    }
  }
  if (tsr == 2) {
    __syncthreads();
    // coalesced copy-out: vgT[bn][co][t0 + t], 1024 chunks of 4 shorts
#pragma unroll
    for (int i = 0; i < 4; ++i) {
      int chunk = tid + 256 * i;
      int co = chunk >> 4, tc = chunk & 15;
      s16x4 v4 = *(const s16x4*)(lxT + co * 64 + ((tc * 4) ^ ((co & 15) << 2)));
      *(s16x4*)(vgT + ((size_t)bn * 64 + co) * TT + t0 + tc * 4) = v4;
    }
  }
}

// ---------------------------------------------------------------------------
// Kernel 2: attention, SPLIT-K.  Grid 1024 = (bn,h,qq), 512 threads = 8
// waves: wave w -> mt = qq*4+(w&3), k-half kh = w>>2 (8 nt each).
// r11 counters (4-wave version): Occupancy 41% (grid-capped at 50%),
// VALUBusy 43%, MfmaUtil 12% -> latency-bound.  8 waves/block = 32 waves/CU
// (100%).  kh=1 waves deposit partial o+sum in LDS; kh=0 combine+normalize.
// Inner body byte-identical to r9's proven schedule (exp2+v_max shield,
// cvtpk, permlane32_swap).
// ---------------------------------------------------------------------------
__global__ __launch_bounds__(512, 8) void k_attn(const short* __restrict__ qg,
                                                 const short* __restrict__ kg,
                                                 const short* __restrict__ vgT,
                                                 short* __restrict__ ag) {
  __shared__ __align__(16) short Kl[512 * 16];   // frag-major: tile nt at nt*512, lane*8
  __shared__ __align__(16) float Po[4][64][16];  // kh=1 partial o
  __shared__ float Psum[4][64];                  // kh=1 partial sums
  __shared__ float Sums[4][32];                  // final denominators per mt
  const int tid = threadIdx.x;
  // bijective XCD swizzle: all 16 (h,qq) blocks of one bn land on one XCD
  const int b = (blockIdx.x & 7) * 128 + (blockIdx.x >> 3);
  const int bn = b >> 4, h = (b >> 2) & 3, qq = b & 3;
  const int lane = tid & 63, w = tid >> 6;
  const int mtw = w & 3, kh = w >> 2;
  const int r = lane & 31, hl = lane >> 5;

  // stage K slice (512 x 16) into fragment-major LDS
  const short* kslice = kg + (size_t)bn * TT * CC + h * 16;
  for (int s = tid; s < 1024; s += 512) {
    int row = s >> 1, hh = s & 1;
    s16x8 kv = *(const s16x8*)(kslice + (size_t)row * CC + hh * 8);
    *(s16x8*)(Kl + (row >> 5) * 512 + (row & 31) * 8 + hh * 256) = kv;
  }

  const int mt = qq * 4 + mtw;
  s16x8 qf = *(const s16x8*)(qg + ((size_t)bn * TT + mt * 32 + r) * CC + h * 16 + hl * 8);
  const short* vb = vgT + ((size_t)bn * 64 + h * 16 + (r & 15)) * TT;

  __syncthreads();

  f32x16 z;
#pragma unroll
  for (int i = 0; i < 16; ++i) z[i] = 0.f;
  float sm0 = 0.f, sm1 = 0.f, sm2 = 0.f, sm3 = 0.f;
  f32x16 o;
#pragma unroll
  for (int i = 0; i < 16; ++i) o[i] = 0.f;

#pragma unroll
  for (int i8 = 0; i8 < 8; ++i8) {
    int nt = kh * 8 + i8;
    s16x8 kf = *(const s16x8*)(Kl + nt * 512 + lane * 8);
    f32x16 s = __builtin_amdgcn_mfma_f32_32x32x16_bf16(kf, qf, z, 0, 0, 0);
    float p[16];
#pragma unroll
    for (int i = 0; i < 16; ++i)
      p[i] = fmaxf(__builtin_amdgcn_exp2f(s[i]), 0.f);  // v_max shields asm consumer
#pragma unroll
    for (int i = 0; i < 4; ++i) {
      sm0 += p[4 * i + 0]; sm1 += p[4 * i + 1];
      sm2 += p[4 * i + 2]; sm3 += p[4 * i + 3];
    }
    unsigned pk[8];
#pragma unroll
    for (int m = 0; m < 8; ++m) pk[m] = cvtpk(p[2 * m], p[2 * m + 1]);
#pragma unroll
    for (int s2 = 0; s2 < 2; ++s2) {
      unsigned a0 = pk[4 * s2 + 0], b0 = pk[4 * s2 + 2];
      unsigned a1 = pk[4 * s2 + 1], b1 = pk[4 * s2 + 3];
      asm("v_permlane32_swap_b32 %0, %1" : "+v"(a0), "+v"(b0));
      asm("v_permlane32_swap_b32 %0, %1" : "+v"(a1), "+v"(b1));
      u32x4 fw; fw[0] = a0; fw[1] = a1; fw[2] = b0; fw[3] = b1;
      s16x8 fr = __builtin_bit_cast(s16x8, fw);
      s16x8 vf = *(const s16x8*)(vb + nt * 32 + s2 * 16 + hl * 8);
      o = __builtin_amdgcn_mfma_f32_32x32x16_bf16(fr, vf, o, 0, 0, 0);
    }
  }
  float sum = (sm0 + sm1) + (sm2 + sm3);
  sum += __shfl_xor(sum, 32);

  if (kh == 1) {
#pragma unroll
    for (int reg = 0; reg < 16; ++reg) Po[mtw][lane][reg] = o[reg];
    Psum[mtw][lane] = sum;
  }
  __syncthreads();
  if (kh == 0) {
#pragma unroll
    for (int reg = 0; reg < 16; ++reg) o[reg] += Po[mtw][lane][reg];
    sum += Psum[mtw][lane];
    Sums[mtw][r] = sum;      // lanes r and r+32 write identical values
    if (r < 16) {
#pragma unroll
      for (int reg = 0; reg < 16; ++reg) {
        int qlocal = (reg & 3) + 8 * (reg >> 2) + 4 * hl;
        float inv = __builtin_amdgcn_rcpf(Sums[mtw][qlocal]);
        int q = mt * 32 + qlocal;
        ag[((size_t)bn * TT + q) * CC + h * 16 + r] = f2bf(o[reg] * inv);
      }
    }
  }
}

// ---------------------------------------------------------------------------
// Kernel 3: final linear out = attn @ Wf^T + bf (fp32 out).
// Grid 512 (64-row tiles), 1 job/wave (r11 version, proven).
// ---------------------------------------------------------------------------
__global__ __launch_bounds__(256) void k_out(const short* __restrict__ ag,
                                             const short* __restrict__ wfb,
                                             const float* __restrict__ bfv,
                                             float* __restrict__ out) {
  __shared__ __align__(16) short la[64 * 64];
  const int tid = threadIdx.x;
  const int bn = blockIdx.x >> 3, t8 = blockIdx.x & 7;
  const int t0 = t8 * 64;
  for (int s = tid; s < 64 * 8; s += 256) {
    int row = s >> 3, c8 = s & 7;
    s16x8 v = *(const s16x8*)(ag + ((size_t)bn * TT + t0 + row) * 64 + c8 * 8);
    int byte = row * 128 + ((c8 * 16) ^ ((row & 7) << 4));
    *(s16x8*)((char*)la + byte) = v;
  }
  __syncthreads();
  const int lane = tid & 63, w = tid >> 6;
  const int r = lane & 31, hl = lane >> 5;
  {
    int mt = w >> 1, nt = w & 1;
    f32x16 acc;
#pragma unroll
    for (int i = 0; i < 16; ++i) acc[i] = 0.f;
#pragma unroll
    for (int c4 = 0; c4 < 4; ++c4) {
      int lrow = mt * 32 + r;
      int abyte = lrow * 128 + (((c4 * 16 + hl * 8) * 2) ^ ((lrow & 7) << 4));
      s16x8 af = *(const s16x8*)((const char*)la + abyte);
      s16x8 bfr = *(const s16x8*)(wfb + (nt * 32 + r) * 64 + c4 * 16 + hl * 8);
      acc = __builtin_amdgcn_mfma_f32_32x32x16_bf16(af, bfr, acc, 0, 0, 0);
    }
    int co = nt * 32 + r;
    float bias = bfv[co];
#pragma unroll
    for (int reg = 0; reg < 16; ++reg) {
      int trow = mt * 32 + (reg & 3) + 8 * (reg >> 2) + 4 * hl;
      out[((size_t)bn * TT + t0 + trow) * 64 + co] = acc[reg] + bias;
    }
  }
}

// ---------------------------------------------------------------------------
extern "C" void kernel_launch(void* const* d_in, const int* in_sizes, int n_in,
                              void* d_out, int out_size, void* d_ws, size_t ws_size,
                              hipStream_t stream) {
  const float* values = (const float*)d_in[0];
  const float* keys = (const float*)d_in[1];
  const float* query = (const float*)d_in[2];
  const float* Wq = (const float*)d_in[3];
  const float* bq = (const float*)d_in[4];
  const float* Wk = (const float*)d_in[5];
  const float* bk = (const float*)d_in[6];
  const float* Wv = (const float*)d_in[7];
  const float* Wf = (const float*)d_in[8];
  const float* bfv = (const float*)d_in[9];
  float* out = (float*)d_out;

  char* ws = (char*)d_ws;
  short* wsw = (short*)ws;                              // 64 KiB weights
  short* qg = (short*)(ws + (1 << 16));                 // 4 MiB each
  short* kg = (short*)(ws + (1 << 16) + (1 << 22));
  short* vgT = (short*)(ws + (1 << 16) + 2 * (1 << 22));
  short* ag = (short*)(ws + (1 << 16) + 3 * (size_t)(1 << 22));

  hipLaunchKernelGGL(k_prep, dim3(128), dim3(256), 0, stream, Wq, Wk, Wv, Wf, wsw);
  hipLaunchKernelGGL(k_qkv, dim3(1536), dim3(256), 0, stream,
                     values, keys, query, bq, bk, wsw, qg, kg, vgT);
  hipLaunchKernelGGL(k_attn, dim3(1024), dim3(512), 0, stream, qg, kg, vgT, ag);
  hipLaunchKernelGGL(k_out, dim3(512), dim3(256), 0, stream, ag, wsw + 28672, bfv, out);
}

// Round 13
// 49.393 us; speedup vs baseline: 4.1192x; 1.0055x over previous
//
#include <hip/hip_runtime.h>

#define DEVI __device__ __forceinline__

typedef __attribute__((ext_vector_type(8)))  short s16x8;
typedef __attribute__((ext_vector_type(4)))  short s16x4;
typedef __attribute__((ext_vector_type(4)))  float f32x4;
typedef __attribute__((ext_vector_type(16))) float f32x16;
typedef __attribute__((ext_vector_type(2)))  unsigned u32x2;
typedef __attribute__((ext_vector_type(4)))  unsigned u32x4;

// float -> bf16 (RNE), bit pattern as short
DEVI short f2bf(float f) {
  unsigned u = __builtin_bit_cast(unsigned, f);
  u = u + 0x7fffu + ((u >> 16) & 1u);
  return (short)(u >> 16);
}
// two floats -> packed bf16 pair via HW cvt (RNE)
DEVI unsigned cvtpk(float lo, float hi) {
  unsigned r;
  asm("v_cvt_pk_bf16_f32 %0, %1, %2" : "=v"(r) : "v"(lo), "v"(hi));
  return r;
}

constexpr int TT = 512;
constexpr int CC = 64;
constexpr float SCLQ = 0.18033688011112042f;  // log2(e)/8, folded into Q

// ---------------------------------------------------------------------------
// Kernel 0: weight repack fp32 -> bf16.  WqB[kk][co][ci] = Wq[co][ci][kk]
// ---------------------------------------------------------------------------
__global__ __launch_bounds__(256) void k_prep(const float* __restrict__ Wq,
                                              const float* __restrict__ Wk,
                                              const float* __restrict__ Wv,
                                              const float* __restrict__ Wf,
                                              short* __restrict__ wsw) {
  int i = blockIdx.x * 256 + threadIdx.x;
  const int total = 12288 + 12288 + 4096 + 4096;
  if (i >= total) return;
  if (i < 12288) {
    int kk = i >> 12, rem = i & 4095;
    wsw[(kk << 12) + rem] = f2bf(Wq[rem * 3 + kk]);
  } else if (i < 24576) {
    int j = i - 12288;
    int kk = j >> 12, rem = j & 4095;
    wsw[12288 + (kk << 12) + rem] = f2bf(Wk[rem * 3 + kk]);
  } else if (i < 28672) {
    int j = i - 24576;
    wsw[24576 + j] = f2bf(Wv[j]);
  } else {
    int j = i - 28672;
    wsw[28672 + j] = f2bf(Wf[j]);
  }
}

// ---------------------------------------------------------------------------
// Kernel 1: QKV projections (r11 occupancy-fixed version, proven).
// Grid 1536 = tensor(3) x bn(64) x t-tile(8 of 64 rows).
// ---------------------------------------------------------------------------
__global__ __launch_bounds__(256) void k_qkv(const float* __restrict__ values,
                                             const float* __restrict__ keys,
                                             const float* __restrict__ query,
                                             const float* __restrict__ bq,
                                             const float* __restrict__ bk,
                                             const short* __restrict__ wsw,
                                             short* __restrict__ qg,
                                             short* __restrict__ kg,
                                             short* __restrict__ vgT) {
  __shared__ __align__(16) short lx[66 * 64];   // input tile (66 rows w/ halo)
  __shared__ __align__(16) short lxT[64 * 64];  // V transpose tile [co][t]
  const int idx = blockIdx.x;
  const int tsr = idx >> 9;                 // 0=Q 1=K 2=V
  const int sub = idx & 511;
  const int bn = sub >> 3, t8 = sub & 7;
  const int t0 = t8 * 64;
  const size_t xbase = (size_t)bn * TT * CC;
  const int tid = threadIdx.x;
  const int lane = tid & 63, w = tid >> 6;
  const int r = lane & 31, hl = lane >> 5;

  const float* in = (tsr == 0) ? query : (tsr == 1) ? keys : values;
  const int nrows = (tsr < 2) ? 66 : 64;
  const int halo = (tsr < 2) ? 2 : 0;

  // stage input rows [t0-halo, t0+64) as bf16, XOR-swizzled 128B rows
  for (int s = tid; s < nrows * 8; s += 256) {
    int row = s >> 3, c8 = s & 7;
    int t = t0 - halo + row;
    u32x4 rv;
    if (t >= 0) {
      const float4 a = *(const float4*)(in + xbase + (size_t)t * 64 + c8 * 8);
      const float4 b = *(const float4*)(in + xbase + (size_t)t * 64 + c8 * 8 + 4);
      rv[0] = cvtpk(a.x, a.y); rv[1] = cvtpk(a.z, a.w);
      rv[2] = cvtpk(b.x, b.y); rv[3] = cvtpk(b.z, b.w);
    } else {
      rv = (u32x4)(0u);
    }
    int byte = row * 128 + ((c8 * 16) ^ ((row & 7) << 4));
    *(u32x4*)((char*)lx + byte) = rv;
  }
  __syncthreads();

  // 4 jobs: mt(2) x nt(2); wave w takes job w
  {
    int mt = w >> 1, nt = w & 1;
    f32x16 acc;
#pragma unroll
    for (int i = 0; i < 16; ++i) acc[i] = 0.f;

    if (tsr < 2) {
      const short* wb = tsr ? (wsw + 12288) : wsw;   // [3][64][64]
#pragma unroll
      for (int kk = 0; kk < 3; ++kk) {
#pragma unroll
        for (int c4 = 0; c4 < 4; ++c4) {
          int lrow = mt * 32 + r + kk;
          int abyte = lrow * 128 + (((c4 * 16 + hl * 8) * 2) ^ ((lrow & 7) << 4));
          s16x8 af = *(const s16x8*)((const char*)lx + abyte);
          s16x8 bfr = *(const s16x8*)(wb + kk * 4096 + (nt * 32 + r) * 64 + c4 * 16 + hl * 8);
          acc = __builtin_amdgcn_mfma_f32_32x32x16_bf16(af, bfr, acc, 0, 0, 0);
        }
      }
    } else {
      const short* wvb = wsw + 24576;                // [64][64]
#pragma unroll
      for (int c4 = 0; c4 < 4; ++c4) {
        int lrow = mt * 32 + r;
        int abyte = lrow * 128 + (((c4 * 16 + hl * 8) * 2) ^ ((lrow & 7) << 4));
        s16x8 af = *(const s16x8*)((const char*)lx + abyte);
        s16x8 bfr = *(const s16x8*)(wvb + (nt * 32 + r) * 64 + c4 * 16 + hl * 8);
        acc = __builtin_amdgcn_mfma_f32_32x32x16_bf16(af, bfr, acc, 0, 0, 0);
      }
    }
    int co = nt * 32 + r;
    if (tsr == 2) {
      // write transposed to LDS: lxT[co][t_local], XOR-swizzled 4-chunks
#pragma unroll
      for (int g2 = 0; g2 < 4; ++g2) {
        int tl = mt * 32 + g2 * 8 + hl * 4;
        u32x2 pk;
        pk[0] = cvtpk(acc[g2 * 4 + 0], acc[g2 * 4 + 1]);
        pk[1] = cvtpk(acc[g2 * 4 + 2], acc[g2 * 4 + 3]);
        *(u32x2*)(lxT + co * 64 + (tl ^ ((co & 15) << 2))) = pk;
      }
    } else {
      float bias = tsr ? bk[co] : bq[co];
      float scl = tsr ? 1.f : SCLQ;
      short* dst = tsr ? kg : qg;
#pragma unroll
      for (int reg = 0; reg < 16; ++reg) {
        int trow = mt * 32 + (reg & 3) + 8 * (reg >> 2) + 4 * hl;
        dst[((size_t)bn * TT + (t0 + trow)) * 64 + co] = f2bf((acc[reg] + bias) * scl);
      }
    }
  }
  if (tsr == 2) {
    __syncthreads();
    // coalesced copy-out: vgT[bn][co][t0 + t], 1024 chunks of 4 shorts
#pragma unroll
    for (int i = 0; i < 4; ++i) {
      int chunk = tid + 256 * i;
      int co = chunk >> 4, tc = chunk & 15;
      s16x4 v4 = *(const s16x4*)(lxT + co * 64 + ((tc * 4) ^ ((co & 15) << 2)));
      *(s16x4*)(vgT + ((size_t)bn * 64 + co) * TT + t0 + tc * 4) = v4;
    }
  }
}

// ---------------------------------------------------------------------------
// Kernel 2: attention, SPLIT-K, REGISTER-TRIMMED to fit the 64-VGPR cap that
// __launch_bounds__(512,8) imposes (r12 likely spilled: r11 measured exactly
// 64 VGPR before the split-K additions).  Trims: (1) zero C-operand declared
// INSIDE the nt loop (rematerializable, not 16 pinned regs); (2) exp->cvtpk
// interleaved in chunks of 4 (4 live p, was 16); (3) 2 sum accumulators.
// Grid 1024 = (bn,h,qq), 512 thr = 8 waves: wave w -> mt=qq*4+(w&3),
// k-half kh=w>>2.  kh=1 deposits partial o+sum in LDS; kh=0 combines.
// ---------------------------------------------------------------------------
__global__ __launch_bounds__(512, 8) void k_attn(const short* __restrict__ qg,
                                                 const short* __restrict__ kg,
                                                 const short* __restrict__ vgT,
                                                 short* __restrict__ ag) {
  __shared__ __align__(16) short Kl[512 * 16];   // frag-major: tile nt at nt*512, lane*8
  __shared__ __align__(16) float Po[4][64][16];  // kh=1 partial o
  __shared__ float Psum[4][64];                  // kh=1 partial sums
  __shared__ float Sums[4][32];                  // final denominators per mt
  const int tid = threadIdx.x;
  // bijective XCD swizzle: all 16 (h,qq) blocks of one bn land on one XCD
  const int b = (blockIdx.x & 7) * 128 + (blockIdx.x >> 3);
  const int bn = b >> 4, h = (b >> 2) & 3, qq = b & 3;
  const int lane = tid & 63, w = tid >> 6;
  const int mtw = w & 3, kh = w >> 2;
  const int r = lane & 31, hl = lane >> 5;

  // stage K slice (512 x 16) into fragment-major LDS
  const short* kslice = kg + (size_t)bn * TT * CC + h * 16;
  for (int s = tid; s < 1024; s += 512) {
    int row = s >> 1, hh = s & 1;
    s16x8 kv = *(const s16x8*)(kslice + (size_t)row * CC + hh * 8);
    *(s16x8*)(Kl + (row >> 5) * 512 + (row & 31) * 8 + hh * 256) = kv;
  }

  const int mt = qq * 4 + mtw;
  s16x8 qf = *(const s16x8*)(qg + ((size_t)bn * TT + mt * 32 + r) * CC + h * 16 + hl * 8);
  const short* vb = vgT + ((size_t)bn * 64 + h * 16 + (r & 15)) * TT;

  __syncthreads();

  float sm0 = 0.f, sm1 = 0.f;
  f32x16 o;
#pragma unroll
  for (int i = 0; i < 16; ++i) o[i] = 0.f;

#pragma unroll
  for (int i8 = 0; i8 < 8; ++i8) {
    int nt = kh * 8 + i8;
    s16x8 kf = *(const s16x8*)(Kl + nt * 512 + lane * 8);
    f32x16 z;
#pragma unroll
    for (int i = 0; i < 16; ++i) z[i] = 0.f;   // short live range -> remat
    f32x16 s = __builtin_amdgcn_mfma_f32_32x32x16_bf16(kf, qf, z, 0, 0, 0);
    unsigned pk[8];
#pragma unroll
    for (int g2 = 0; g2 < 4; ++g2) {           // 4 live p at a time
      float p0 = fmaxf(__builtin_amdgcn_exp2f(s[4 * g2 + 0]), 0.f);
      float p1 = fmaxf(__builtin_amdgcn_exp2f(s[4 * g2 + 1]), 0.f);
      float p2 = fmaxf(__builtin_amdgcn_exp2f(s[4 * g2 + 2]), 0.f);
      float p3 = fmaxf(__builtin_amdgcn_exp2f(s[4 * g2 + 3]), 0.f);
      sm0 += p0 + p2;
      sm1 += p1 + p3;
      pk[2 * g2] = cvtpk(p0, p1);
      pk[2 * g2 + 1] = cvtpk(p2, p3);
    }
#pragma unroll
    for (int s2 = 0; s2 < 2; ++s2) {
      unsigned a0 = pk[4 * s2 + 0], b0 = pk[4 * s2 + 2];
      unsigned a1 = pk[4 * s2 + 1], b1 = pk[4 * s2 + 3];
      asm("v_permlane32_swap_b32 %0, %1" : "+v"(a0), "+v"(b0));
      asm("v_permlane32_swap_b32 %0, %1" : "+v"(a1), "+v"(b1));
      u32x4 fw; fw[0] = a0; fw[1] = a1; fw[2] = b0; fw[3] = b1;
      s16x8 fr = __builtin_bit_cast(s16x8, fw);
      s16x8 vf = *(const s16x8*)(vb + nt * 32 + s2 * 16 + hl * 8);
      o = __builtin_amdgcn_mfma_f32_32x32x16_bf16(fr, vf, o, 0, 0, 0);
    }
  }
  float sum = sm0 + sm1;
  sum += __shfl_xor(sum, 32);

  if (kh == 1) {
#pragma unroll
    for (int reg = 0; reg < 16; ++reg) Po[mtw][lane][reg] = o[reg];
    Psum[mtw][lane] = sum;
  }
  __syncthreads();
  if (kh == 0) {
#pragma unroll
    for (int reg = 0; reg < 16; ++reg) o[reg] += Po[mtw][lane][reg];
    sum += Psum[mtw][lane];
    Sums[mtw][r] = sum;      // lanes r and r+32 write identical values
    if (r < 16) {
#pragma unroll
      for (int reg = 0; reg < 16; ++reg) {
        int qlocal = (reg & 3) + 8 * (reg >> 2) + 4 * hl;
        float inv = __builtin_amdgcn_rcpf(Sums[mtw][qlocal]);
        int q = mt * 32 + qlocal;
        ag[((size_t)bn * TT + q) * CC + h * 16 + r] = f2bf(o[reg] * inv);
      }
    }
  }
}

// ---------------------------------------------------------------------------
// Kernel 3: final linear out = attn @ Wf^T + bf (fp32 out).
// Grid 512 (64-row tiles), 1 job/wave (r11 version, proven).
// ---------------------------------------------------------------------------
__global__ __launch_bounds__(256) void k_out(const short* __restrict__ ag,
                                             const short* __restrict__ wfb,
                                             const float* __restrict__ bfv,
                                             float* __restrict__ out) {
  __shared__ __align__(16) short la[64 * 64];
  const int tid = threadIdx.x;
  const int bn = blockIdx.x >> 3, t8 = blockIdx.x & 7;
  const int t0 = t8 * 64;
  for (int s = tid; s < 64 * 8; s += 256) {
    int row = s >> 3, c8 = s & 7;
    s16x8 v = *(const s16x8*)(ag + ((size_t)bn * TT + t0 + row) * 64 + c8 * 8);
    int byte = row * 128 + ((c8 * 16) ^ ((row & 7) << 4));
    *(s16x8*)((char*)la + byte) = v;
  }
  __syncthreads();
  const int lane = tid & 63, w = tid >> 6;
  const int r = lane & 31, hl = lane >> 5;
  {
    int mt = w >> 1, nt = w & 1;
    f32x16 acc;
#pragma unroll
    for (int i = 0; i < 16; ++i) acc[i] = 0.f;
#pragma unroll
    for (int c4 = 0; c4 < 4; ++c4) {
      int lrow = mt * 32 + r;
      int abyte = lrow * 128 + (((c4 * 16 + hl * 8) * 2) ^ ((lrow & 7) << 4));
      s16x8 af = *(const s16x8*)((const char*)la + abyte);
      s16x8 bfr = *(const s16x8*)(wfb + (nt * 32 + r) * 64 + c4 * 16 + hl * 8);
      acc = __builtin_amdgcn_mfma_f32_32x32x16_bf16(af, bfr, acc, 0, 0, 0);
    }
    int co = nt * 32 + r;
    float bias = bfv[co];
#pragma unroll
    for (int reg = 0; reg < 16; ++reg) {
      int trow = mt * 32 + (reg & 3) + 8 * (reg >> 2) + 4 * hl;
      out[((size_t)bn * TT + t0 + trow) * 64 + co] = acc[reg] + bias;
    }
  }
}

// ---------------------------------------------------------------------------
extern "C" void kernel_launch(void* const* d_in, const int* in_sizes, int n_in,
                              void* d_out, int out_size, void* d_ws, size_t ws_size,
                              hipStream_t stream) {
  const float* values = (const float*)d_in[0];
  const float* keys = (const float*)d_in[1];
  const float* query = (const float*)d_in[2];
  const float* Wq = (const float*)d_in[3];
  const float* bq = (const float*)d_in[4];
  const float* Wk = (const float*)d_in[5];
  const float* bk = (const float*)d_in[6];
  const float* Wv = (const float*)d_in[7];
  const float* Wf = (const float*)d_in[8];
  const float* bfv = (const float*)d_in[9];
  float* out = (float*)d_out;

  char* ws = (char*)d_ws;
  short* wsw = (short*)ws;                              // 64 KiB weights
  short* qg = (short*)(ws + (1 << 16));                 // 4 MiB each
  short* kg = (short*)(ws + (1 << 16) + (1 << 22));
  short* vgT = (short*)(ws + (1 << 16) + 2 * (1 << 22));
  short* ag = (short*)(ws + (1 << 16) + 3 * (size_t)(1 << 22));

  hipLaunchKernelGGL(k_prep, dim3(128), dim3(256), 0, stream, Wq, Wk, Wv, Wf, wsw);
  hipLaunchKernelGGL(k_qkv, dim3(1536), dim3(256), 0, stream,
                     values, keys, query, bq, bk, wsw, qg, kg, vgT);
  hipLaunchKernelGGL(k_attn, dim3(1024), dim3(512), 0, stream, qg, kg, vgT, ag);
  hipLaunchKernelGGL(k_out, dim3(512), dim3(256), 0, stream, ag, wsw + 28672, bfv, out);
}

// Round 14
// 49.301 us; speedup vs baseline: 4.1269x; 1.0019x over previous
//
#include <hip/hip_runtime.h>

#define DEVI __device__ __forceinline__

typedef __attribute__((ext_vector_type(8)))  short s16x8;
typedef __attribute__((ext_vector_type(4)))  short s16x4;
typedef __attribute__((ext_vector_type(4)))  float f32x4;
typedef __attribute__((ext_vector_type(16))) float f32x16;
typedef __attribute__((ext_vector_type(2)))  unsigned u32x2;
typedef __attribute__((ext_vector_type(4)))  unsigned u32x4;

// float -> bf16 (RNE), bit pattern as short
DEVI short f2bf(float f) {
  unsigned u = __builtin_bit_cast(unsigned, f);
  u = u + 0x7fffu + ((u >> 16) & 1u);
  return (short)(u >> 16);
}
// two floats -> packed bf16 pair via HW cvt (RNE)
DEVI unsigned cvtpk(float lo, float hi) {
  unsigned r;
  asm("v_cvt_pk_bf16_f32 %0, %1, %2" : "=v"(r) : "v"(lo), "v"(hi));
  return r;
}

constexpr int TT = 512;
constexpr int CC = 64;
constexpr float SCLQ = 0.18033688011112042f;  // log2(e)/8, folded into Q

// ---------------------------------------------------------------------------
// Kernel 0: weight repack fp32 -> bf16.  WqB[kk][co][ci] = Wq[co][ci][kk]
// ---------------------------------------------------------------------------
__global__ __launch_bounds__(256) void k_prep(const float* __restrict__ Wq,
                                              const float* __restrict__ Wk,
                                              const float* __restrict__ Wv,
                                              const float* __restrict__ Wf,
                                              short* __restrict__ wsw) {
  int i = blockIdx.x * 256 + threadIdx.x;
  const int total = 12288 + 12288 + 4096 + 4096;
  if (i >= total) return;
  if (i < 12288) {
    int kk = i >> 12, rem = i & 4095;
    wsw[(kk << 12) + rem] = f2bf(Wq[rem * 3 + kk]);
  } else if (i < 24576) {
    int j = i - 12288;
    int kk = j >> 12, rem = j & 4095;
    wsw[12288 + (kk << 12) + rem] = f2bf(Wk[rem * 3 + kk]);
  } else if (i < 28672) {
    int j = i - 24576;
    wsw[24576 + j] = f2bf(Wv[j]);
  } else {
    int j = i - 28672;
    wsw[28672 + j] = f2bf(Wf[j]);
  }
}

// ---------------------------------------------------------------------------
// Kernel 1: QKV projections (r11 occupancy-fixed version, proven).
// Grid 1536 = tensor(3) x bn(64) x t-tile(8 of 64 rows).
// ---------------------------------------------------------------------------
__global__ __launch_bounds__(256) void k_qkv(const float* __restrict__ values,
                                             const float* __restrict__ keys,
                                             const float* __restrict__ query,
                                             const float* __restrict__ bq,
                                             const float* __restrict__ bk,
                                             const short* __restrict__ wsw,
                                             short* __restrict__ qg,
                                             short* __restrict__ kg,
                                             short* __restrict__ vgT) {
  __shared__ __align__(16) short lx[66 * 64];   // input tile (66 rows w/ halo)
  __shared__ __align__(16) short lxT[64 * 64];  // V transpose tile [co][t]
  const int idx = blockIdx.x;
  const int tsr = idx >> 9;                 // 0=Q 1=K 2=V
  const int sub = idx & 511;
  const int bn = sub >> 3, t8 = sub & 7;
  const int t0 = t8 * 64;
  const size_t xbase = (size_t)bn * TT * CC;
  const int tid = threadIdx.x;
  const int lane = tid & 63, w = tid >> 6;
  const int r = lane & 31, hl = lane >> 5;

  const float* in = (tsr == 0) ? query : (tsr == 1) ? keys : values;
  const int nrows = (tsr < 2) ? 66 : 64;
  const int halo = (tsr < 2) ? 2 : 0;

  // stage input rows [t0-halo, t0+64) as bf16, XOR-swizzled 128B rows
  for (int s = tid; s < nrows * 8; s += 256) {
    int row = s >> 3, c8 = s & 7;
    int t = t0 - halo + row;
    u32x4 rv;
    if (t >= 0) {
      const float4 a = *(const float4*)(in + xbase + (size_t)t * 64 + c8 * 8);
      const float4 b = *(const float4*)(in + xbase + (size_t)t * 64 + c8 * 8 + 4);
      rv[0] = cvtpk(a.x, a.y); rv[1] = cvtpk(a.z, a.w);
      rv[2] = cvtpk(b.x, b.y); rv[3] = cvtpk(b.z, b.w);
    } else {
      rv = (u32x4)(0u);
    }
    int byte = row * 128 + ((c8 * 16) ^ ((row & 7) << 4));
    *(u32x4*)((char*)lx + byte) = rv;
  }
  __syncthreads();

  // 4 jobs: mt(2) x nt(2); wave w takes job w
  {
    int mt = w >> 1, nt = w & 1;
    f32x16 acc;
#pragma unroll
    for (int i = 0; i < 16; ++i) acc[i] = 0.f;

    if (tsr < 2) {
      const short* wb = tsr ? (wsw + 12288) : wsw;   // [3][64][64]
#pragma unroll
      for (int kk = 0; kk < 3; ++kk) {
#pragma unroll
        for (int c4 = 0; c4 < 4; ++c4) {
          int lrow = mt * 32 + r + kk;
          int abyte = lrow * 128 + (((c4 * 16 + hl * 8) * 2) ^ ((lrow & 7) << 4));
          s16x8 af = *(const s16x8*)((const char*)lx + abyte);
          s16x8 bfr = *(const s16x8*)(wb + kk * 4096 + (nt * 32 + r) * 64 + c4 * 16 + hl * 8);
          acc = __builtin_amdgcn_mfma_f32_32x32x16_bf16(af, bfr, acc, 0, 0, 0);
        }
      }
    } else {
      const short* wvb = wsw + 24576;                // [64][64]
#pragma unroll
      for (int c4 = 0; c4 < 4; ++c4) {
        int lrow = mt * 32 + r;
        int abyte = lrow * 128 + (((c4 * 16 + hl * 8) * 2) ^ ((lrow & 7) << 4));
        s16x8 af = *(const s16x8*)((const char*)lx + abyte);
        s16x8 bfr = *(const s16x8*)(wvb + (nt * 32 + r) * 64 + c4 * 16 + hl * 8);
        acc = __builtin_amdgcn_mfma_f32_32x32x16_bf16(af, bfr, acc, 0, 0, 0);
      }
    }
    int co = nt * 32 + r;
    if (tsr == 2) {
      // write transposed to LDS: lxT[co][t_local], XOR-swizzled 4-chunks
#pragma unroll
      for (int g2 = 0; g2 < 4; ++g2) {
        int tl = mt * 32 + g2 * 8 + hl * 4;
        u32x2 pk;
        pk[0] = cvtpk(acc[g2 * 4 + 0], acc[g2 * 4 + 1]);
        pk[1] = cvtpk(acc[g2 * 4 + 2], acc[g2 * 4 + 3]);
        *(u32x2*)(lxT + co * 64 + (tl ^ ((co & 15) << 2))) = pk;
      }
    } else {
      float bias = tsr ? bk[co] : bq[co];
      float scl = tsr ? 1.f : SCLQ;
      short* dst = tsr ? kg : qg;
#pragma unroll
      for (int reg = 0; reg < 16; ++reg) {
        int trow = mt * 32 + (reg & 3) + 8 * (reg >> 2) + 4 * hl;
        dst[((size_t)bn * TT + (t0 + trow)) * 64 + co] = f2bf((acc[reg] + bias) * scl);
      }
    }
  }
  if (tsr == 2) {
    __syncthreads();
    // coalesced copy-out: vgT[bn][co][t0 + t], 1024 chunks of 4 shorts
#pragma unroll
    for (int i = 0; i < 4; ++i) {
      int chunk = tid + 256 * i;
      int co = chunk >> 4, tc = chunk & 15;
      s16x4 v4 = *(const s16x4*)(lxT + co * 64 + ((tc * 4) ^ ((co & 15) << 2)));
      *(s16x4*)(vgT + ((size_t)bn * 64 + co) * TT + t0 + tc * 4) = v4;
    }
  }
}

// ---------------------------------------------------------------------------
// Kernel 2: attention — r9 4-wave body, UNDILATED (first clean bench of the
// proven-best config: r11 measured this body at ~20.6us/rep under dilation;
// split-K (r12/r13) was a regression and is reverted).
// Grid 1024 = (bn,h,qq); 4 waves, 1 mt/wave.  One-pass no-max softmax;
// native exp2 shielded by v_max; P in registers via cvt_pk +
// v_permlane32_swap_b32; explicit fp32 denominator.
// ---------------------------------------------------------------------------
__global__ __launch_bounds__(256, 4) void k_attn(const short* __restrict__ qg,
                                                 const short* __restrict__ kg,
                                                 const short* __restrict__ vgT,
                                                 short* __restrict__ ag) {
  __shared__ __align__(16) short Kl[512 * 16];   // frag-major: tile nt at nt*512, lane*8
  __shared__ float Sums[4][32];
  const int tid = threadIdx.x;
  // bijective XCD swizzle: all 16 (h,qq) blocks of one bn land on one XCD
  const int b = (blockIdx.x & 7) * 128 + (blockIdx.x >> 3);
  const int bn = b >> 4, h = (b >> 2) & 3, qq = b & 3;
  const int lane = tid & 63, w = tid >> 6;
  const int r = lane & 31, hl = lane >> 5;

  // stage K slice (512 x 16) into fragment-major LDS
  const short* kslice = kg + (size_t)bn * TT * CC + h * 16;
  for (int s = tid; s < 1024; s += 256) {
    int row = s >> 1, hh = s & 1;
    s16x8 kv = *(const s16x8*)(kslice + (size_t)row * CC + hh * 8);
    *(s16x8*)(Kl + (row >> 5) * 512 + (row & 31) * 8 + hh * 256) = kv;
  }

  const int mt = qq * 4 + w;
  s16x8 qf = *(const s16x8*)(qg + ((size_t)bn * TT + mt * 32 + r) * CC + h * 16 + hl * 8);
  // per-lane V channel row (r>=16 duplicates r-16; those output cols discarded)
  const short* vb = vgT + ((size_t)bn * 64 + h * 16 + (r & 15)) * TT;

  __syncthreads();

  f32x16 z;
#pragma unroll
  for (int i = 0; i < 16; ++i) z[i] = 0.f;
  float sm0 = 0.f, sm1 = 0.f, sm2 = 0.f, sm3 = 0.f;
  f32x16 o;
#pragma unroll
  for (int i = 0; i < 16; ++i) o[i] = 0.f;

#pragma unroll
  for (int nt = 0; nt < 16; ++nt) {
    s16x8 kf = *(const s16x8*)(Kl + nt * 512 + lane * 8);
    f32x16 s = __builtin_amdgcn_mfma_f32_32x32x16_bf16(kf, qf, z, 0, 0, 0);
    float p[16];
#pragma unroll
    for (int i = 0; i < 16; ++i)
      p[i] = fmaxf(__builtin_amdgcn_exp2f(s[i]), 0.f);  // v_max shields asm consumer
#pragma unroll
    for (int i = 0; i < 4; ++i) {
      sm0 += p[4 * i + 0]; sm1 += p[4 * i + 1];
      sm2 += p[4 * i + 2]; sm3 += p[4 * i + 3];
    }
    unsigned pk[8];
#pragma unroll
    for (int m = 0; m < 8; ++m) pk[m] = cvtpk(p[2 * m], p[2 * m + 1]);
#pragma unroll
    for (int s2 = 0; s2 < 2; ++s2) {
      unsigned a0 = pk[4 * s2 + 0], b0 = pk[4 * s2 + 2];
      unsigned a1 = pk[4 * s2 + 1], b1 = pk[4 * s2 + 3];
      asm("v_permlane32_swap_b32 %0, %1" : "+v"(a0), "+v"(b0));
      asm("v_permlane32_swap_b32 %0, %1" : "+v"(a1), "+v"(b1));
      u32x4 fw; fw[0] = a0; fw[1] = a1; fw[2] = b0; fw[3] = b1;
      s16x8 fr = __builtin_bit_cast(s16x8, fw);
      s16x8 vf = *(const s16x8*)(vb + nt * 32 + s2 * 16 + hl * 8);
      o = __builtin_amdgcn_mfma_f32_32x32x16_bf16(fr, vf, o, 0, 0, 0);
    }
  }
  float sum = (sm0 + sm1) + (sm2 + sm3);
  sum += __shfl_xor(sum, 32);
  Sums[w][r] = sum;
  if (r < 16) {
#pragma unroll
    for (int reg = 0; reg < 16; ++reg) {
      int qlocal = (reg & 3) + 8 * (reg >> 2) + 4 * hl;
      float inv = __builtin_amdgcn_rcpf(Sums[w][qlocal]);
      int q = mt * 32 + qlocal;
      ag[((size_t)bn * TT + q) * CC + h * 16 + r] = f2bf(o[reg] * inv);
    }
  }
}

// ---------------------------------------------------------------------------
// Kernel 3: final linear out = attn @ Wf^T + bf (fp32 out).
// Grid 512 (64-row tiles), 1 job/wave (r11 version, proven).
// ---------------------------------------------------------------------------
__global__ __launch_bounds__(256) void k_out(const short* __restrict__ ag,
                                             const short* __restrict__ wfb,
                                             const float* __restrict__ bfv,
                                             float* __restrict__ out) {
  __shared__ __align__(16) short la[64 * 64];
  const int tid = threadIdx.x;
  const int bn = blockIdx.x >> 3, t8 = blockIdx.x & 7;
  const int t0 = t8 * 64;
  for (int s = tid; s < 64 * 8; s += 256) {
    int row = s >> 3, c8 = s & 7;
    s16x8 v = *(const s16x8*)(ag + ((size_t)bn * TT + t0 + row) * 64 + c8 * 8);
    int byte = row * 128 + ((c8 * 16) ^ ((row & 7) << 4));
    *(s16x8*)((char*)la + byte) = v;
  }
  __syncthreads();
  const int lane = tid & 63, w = tid >> 6;
  const int r = lane & 31, hl = lane >> 5;
  {
    int mt = w >> 1, nt = w & 1;
    f32x16 acc;
#pragma unroll
    for (int i = 0; i < 16; ++i) acc[i] = 0.f;
#pragma unroll
    for (int c4 = 0; c4 < 4; ++c4) {
      int lrow = mt * 32 + r;
      int abyte = lrow * 128 + (((c4 * 16 + hl * 8) * 2) ^ ((lrow & 7) << 4));
      s16x8 af = *(const s16x8*)((const char*)la + abyte);
      s16x8 bfr = *(const s16x8*)(wfb + (nt * 32 + r) * 64 + c4 * 16 + hl * 8);
      acc = __builtin_amdgcn_mfma_f32_32x32x16_bf16(af, bfr, acc, 0, 0, 0);
    }
    int co = nt * 32 + r;
    float bias = bfv[co];
#pragma unroll
    for (int reg = 0; reg < 16; ++reg) {
      int trow = mt * 32 + (reg & 3) + 8 * (reg >> 2) + 4 * hl;
      out[((size_t)bn * TT + t0 + trow) * 64 + co] = acc[reg] + bias;
    }
  }
}

// ---------------------------------------------------------------------------
extern "C" void kernel_launch(void* const* d_in, const int* in_sizes, int n_in,
                              void* d_out, int out_size, void* d_ws, size_t ws_size,
                              hipStream_t stream) {
  const float* values = (const float*)d_in[0];
  const float* keys = (const float*)d_in[1];
  const float* query = (const float*)d_in[2];
  const float* Wq = (const float*)d_in[3];
  const float* bq = (const float*)d_in[4];
  const float* Wk = (const float*)d_in[5];
  const float* bk = (const float*)d_in[6];
  const float* Wv = (const float*)d_in[7];
  const float* Wf = (const float*)d_in[8];
  const float* bfv = (const float*)d_in[9];
  float* out = (float*)d_out;

  char* ws = (char*)d_ws;
  short* wsw = (short*)ws;                              // 64 KiB weights
  short* qg = (short*)(ws + (1 << 16));                 // 4 MiB each
  short* kg = (short*)(ws + (1 << 16) + (1 << 22));
  short* vgT = (short*)(ws + (1 << 16) + 2 * (1 << 22));
  short* ag = (short*)(ws + (1 << 16) + 3 * (size_t)(1 << 22));

  hipLaunchKernelGGL(k_prep, dim3(128), dim3(256), 0, stream, Wq, Wk, Wv, Wf, wsw);
  hipLaunchKernelGGL(k_qkv, dim3(1536), dim3(256), 0, stream,
                     values, keys, query, bq, bk, wsw, qg, kg, vgT);
  hipLaunchKernelGGL(k_attn, dim3(1024), dim3(256), 0, stream, qg, kg, vgT, ag);
  hipLaunchKernelGGL(k_out, dim3(512), dim3(256), 0, stream, ag, wsw + 28672, bfv, out);
}

// Round 15
// 48.717 us; speedup vs baseline: 4.1763x; 1.0120x over previous
//
#include <hip/hip_runtime.h>

#define DEVI __device__ __forceinline__

typedef __attribute__((ext_vector_type(8)))  short s16x8;
typedef __attribute__((ext_vector_type(4)))  short s16x4;
typedef __attribute__((ext_vector_type(4)))  float f32x4;
typedef __attribute__((ext_vector_type(16))) float f32x16;
typedef __attribute__((ext_vector_type(2)))  unsigned u32x2;
typedef __attribute__((ext_vector_type(4)))  unsigned u32x4;

// float -> bf16 (RNE), bit pattern as short
DEVI short f2bf(float f) {
  unsigned u = __builtin_bit_cast(unsigned, f);
  u = u + 0x7fffu + ((u >> 16) & 1u);
  return (short)(u >> 16);
}
// two floats -> packed bf16 pair via HW cvt (RNE)
DEVI unsigned cvtpk(float lo, float hi) {
  unsigned r;
  asm("v_cvt_pk_bf16_f32 %0, %1, %2" : "=v"(r) : "v"(lo), "v"(hi));
  return r;
}

constexpr int TT = 512;
constexpr int CC = 64;
constexpr float SCLQ = 0.18033688011112042f;  // log2(e)/8, folded into Q

// ---------------------------------------------------------------------------
// Kernel 0: weight repack fp32 -> bf16.  WqB[kk][co][ci] = Wq[co][ci][kk]
// ---------------------------------------------------------------------------
__global__ __launch_bounds__(256) void k_prep(const float* __restrict__ Wq,
                                              const float* __restrict__ Wk,
                                              const float* __restrict__ Wv,
                                              const float* __restrict__ Wf,
                                              short* __restrict__ wsw) {
  int i = blockIdx.x * 256 + threadIdx.x;
  const int total = 12288 + 12288 + 4096 + 4096;
  if (i >= total) return;
  if (i < 12288) {
    int kk = i >> 12, rem = i & 4095;
    wsw[(kk << 12) + rem] = f2bf(Wq[rem * 3 + kk]);
  } else if (i < 24576) {
    int j = i - 12288;
    int kk = j >> 12, rem = j & 4095;
    wsw[12288 + (kk << 12) + rem] = f2bf(Wk[rem * 3 + kk]);
  } else if (i < 28672) {
    int j = i - 24576;
    wsw[24576 + j] = f2bf(Wv[j]);
  } else {
    int j = i - 28672;
    wsw[28672 + j] = f2bf(Wf[j]);
  }
}

// ---------------------------------------------------------------------------
// Kernel 1: QKV projections (r11 occupancy-fixed version, proven).
// Grid 1536 = tensor(3) x bn(64) x t-tile(8 of 64 rows).
// ---------------------------------------------------------------------------
__global__ __launch_bounds__(256) void k_qkv(const float* __restrict__ values,
                                             const float* __restrict__ keys,
                                             const float* __restrict__ query,
                                             const float* __restrict__ bq,
                                             const float* __restrict__ bk,
                                             const short* __restrict__ wsw,
                                             short* __restrict__ qg,
                                             short* __restrict__ kg,
                                             short* __restrict__ vgT) {
  __shared__ __align__(16) short lx[66 * 64];   // input tile (66 rows w/ halo)
  __shared__ __align__(16) short lxT[64 * 64];  // V transpose tile [co][t]
  const int idx = blockIdx.x;
  const int tsr = idx >> 9;                 // 0=Q 1=K 2=V
  const int sub = idx & 511;
  const int bn = sub >> 3, t8 = sub & 7;
  const int t0 = t8 * 64;
  const size_t xbase = (size_t)bn * TT * CC;
  const int tid = threadIdx.x;
  const int lane = tid & 63, w = tid >> 6;
  const int r = lane & 31, hl = lane >> 5;

  const float* in = (tsr == 0) ? query : (tsr == 1) ? keys : values;
  const int nrows = (tsr < 2) ? 66 : 64;
  const int halo = (tsr < 2) ? 2 : 0;

  // stage input rows [t0-halo, t0+64) as bf16, XOR-swizzled 128B rows
  for (int s = tid; s < nrows * 8; s += 256) {
    int row = s >> 3, c8 = s & 7;
    int t = t0 - halo + row;
    u32x4 rv;
    if (t >= 0) {
      const float4 a = *(const float4*)(in + xbase + (size_t)t * 64 + c8 * 8);
      const float4 b = *(const float4*)(in + xbase + (size_t)t * 64 + c8 * 8 + 4);
      rv[0] = cvtpk(a.x, a.y); rv[1] = cvtpk(a.z, a.w);
      rv[2] = cvtpk(b.x, b.y); rv[3] = cvtpk(b.z, b.w);
    } else {
      rv = (u32x4)(0u);
    }
    int byte = row * 128 + ((c8 * 16) ^ ((row & 7) << 4));
    *(u32x4*)((char*)lx + byte) = rv;
  }
  __syncthreads();

  // 4 jobs: mt(2) x nt(2); wave w takes job w
  {
    int mt = w >> 1, nt = w & 1;
    f32x16 acc;
#pragma unroll
    for (int i = 0; i < 16; ++i) acc[i] = 0.f;

    if (tsr < 2) {
      const short* wb = tsr ? (wsw + 12288) : wsw;   // [3][64][64]
#pragma unroll
      for (int kk = 0; kk < 3; ++kk) {
#pragma unroll
        for (int c4 = 0; c4 < 4; ++c4) {
          int lrow = mt * 32 + r + kk;
          int abyte = lrow * 128 + (((c4 * 16 + hl * 8) * 2) ^ ((lrow & 7) << 4));
          s16x8 af = *(const s16x8*)((const char*)lx + abyte);
          s16x8 bfr = *(const s16x8*)(wb + kk * 4096 + (nt * 32 + r) * 64 + c4 * 16 + hl * 8);
          acc = __builtin_amdgcn_mfma_f32_32x32x16_bf16(af, bfr, acc, 0, 0, 0);
        }
      }
    } else {
      const short* wvb = wsw + 24576;                // [64][64]
#pragma unroll
      for (int c4 = 0; c4 < 4; ++c4) {
        int lrow = mt * 32 + r;
        int abyte = lrow * 128 + (((c4 * 16 + hl * 8) * 2) ^ ((lrow & 7) << 4));
        s16x8 af = *(const s16x8*)((const char*)lx + abyte);
        s16x8 bfr = *(const s16x8*)(wvb + (nt * 32 + r) * 64 + c4 * 16 + hl * 8);
        acc = __builtin_amdgcn_mfma_f32_32x32x16_bf16(af, bfr, acc, 0, 0, 0);
      }
    }
    int co = nt * 32 + r;
    if (tsr == 2) {
      // write transposed to LDS: lxT[co][t_local], XOR-swizzled 4-chunks
#pragma unroll
      for (int g2 = 0; g2 < 4; ++g2) {
        int tl = mt * 32 + g2 * 8 + hl * 4;
        u32x2 pk;
        pk[0] = cvtpk(acc[g2 * 4 + 0], acc[g2 * 4 + 1]);
        pk[1] = cvtpk(acc[g2 * 4 + 2], acc[g2 * 4 + 3]);
        *(u32x2*)(lxT + co * 64 + (tl ^ ((co & 15) << 2))) = pk;
      }
    } else {
      float bias = tsr ? bk[co] : bq[co];
      float scl = tsr ? 1.f : SCLQ;
      short* dst = tsr ? kg : qg;
#pragma unroll
      for (int reg = 0; reg < 16; ++reg) {
        int trow = mt * 32 + (reg & 3) + 8 * (reg >> 2) + 4 * hl;
        dst[((size_t)bn * TT + (t0 + trow)) * 64 + co] = f2bf((acc[reg] + bias) * scl);
      }
    }
  }
  if (tsr == 2) {
    __syncthreads();
    // coalesced copy-out: vgT[bn][co][t0 + t], 1024 chunks of 4 shorts
#pragma unroll
    for (int i = 0; i < 4; ++i) {
      int chunk = tid + 256 * i;
      int co = chunk >> 4, tc = chunk & 15;
      s16x4 v4 = *(const s16x4*)(lxT + co * 64 + ((tc * 4) ^ ((co & 15) << 2)));
      *(s16x4*)(vgT + ((size_t)bn * 64 + co) * TT + t0 + tc * 4) = v4;
    }
  }
}

// ---------------------------------------------------------------------------
// Kernel 2: attention, 2-mt-PER-WAVE ILP.  Grid 512 = (bn, h, q-half);
// 4 waves; wave w handles mtA = qq*8+w and mtB = qq*8+4+w.  The two chains
// SHARE kf (same K tile) and vf (V frags are mt-independent) -> per unit
// work, K-LDS reads and V-global loads halve, and two independent
// MFMA->exp->pack->PV chains interleave to cover L2/MFMA latency (r11/r14
// showed the 1-chain version stalls 57% of VALU cycles, and both 4-wave and
// split-K variants land at the same ~30us => latency-bound, not TLP-bound).
// Chain arithmetic byte-identical to the r9-proven body.
// ---------------------------------------------------------------------------
__global__ __launch_bounds__(256, 4) void k_attn(const short* __restrict__ qg,
                                                 const short* __restrict__ kg,
                                                 const short* __restrict__ vgT,
                                                 short* __restrict__ ag) {
  __shared__ __align__(16) short Kl[512 * 16];   // frag-major: tile nt at nt*512, lane*8
  __shared__ float Sums[4][2][32];
  const int tid = threadIdx.x;
  // XCD swizzle: all 8 (h,qq) blocks of one bn land on one XCD
  const int b = (blockIdx.x & 7) * 64 + (blockIdx.x >> 3);
  const int bn = b >> 3, h = (b >> 1) & 3, qq = b & 1;
  const int lane = tid & 63, w = tid >> 6;
  const int r = lane & 31, hl = lane >> 5;

  // stage K slice (512 x 16) into fragment-major LDS
  const short* kslice = kg + (size_t)bn * TT * CC + h * 16;
  for (int s = tid; s < 1024; s += 256) {
    int row = s >> 1, hh = s & 1;
    s16x8 kv = *(const s16x8*)(kslice + (size_t)row * CC + hh * 8);
    *(s16x8*)(Kl + (row >> 5) * 512 + (row & 31) * 8 + hh * 256) = kv;
  }

  const int mtA = qq * 8 + w;
  const int mtB = qq * 8 + 4 + w;
  s16x8 qfA = *(const s16x8*)(qg + ((size_t)bn * TT + mtA * 32 + r) * CC + h * 16 + hl * 8);
  s16x8 qfB = *(const s16x8*)(qg + ((size_t)bn * TT + mtB * 32 + r) * CC + h * 16 + hl * 8);
  // per-lane V channel row (r>=16 duplicates r-16; those output cols discarded)
  const short* vb = vgT + ((size_t)bn * 64 + h * 16 + (r & 15)) * TT;

  __syncthreads();

  float sA0 = 0.f, sA1 = 0.f, sB0 = 0.f, sB1 = 0.f;
  f32x16 oA, oB;
#pragma unroll
  for (int i = 0; i < 16; ++i) { oA[i] = 0.f; oB[i] = 0.f; }

#pragma unroll
  for (int nt = 0; nt < 16; ++nt) {
    s16x8 kf = *(const s16x8*)(Kl + nt * 512 + lane * 8);
    f32x16 z;
#pragma unroll
    for (int i = 0; i < 16; ++i) z[i] = 0.f;
    f32x16 sA = __builtin_amdgcn_mfma_f32_32x32x16_bf16(kf, qfA, z, 0, 0, 0);
    f32x16 sB = __builtin_amdgcn_mfma_f32_32x32x16_bf16(kf, qfB, z, 0, 0, 0);
    unsigned pkA[8], pkB[8];
#pragma unroll
    for (int g2 = 0; g2 < 4; ++g2) {           // chain A, 4 live p at a time
      float p0 = fmaxf(__builtin_amdgcn_exp2f(sA[4 * g2 + 0]), 0.f);
      float p1 = fmaxf(__builtin_amdgcn_exp2f(sA[4 * g2 + 1]), 0.f);
      float p2 = fmaxf(__builtin_amdgcn_exp2f(sA[4 * g2 + 2]), 0.f);
      float p3 = fmaxf(__builtin_amdgcn_exp2f(sA[4 * g2 + 3]), 0.f);
      sA0 += p0 + p2; sA1 += p1 + p3;
      pkA[2 * g2] = cvtpk(p0, p1);
      pkA[2 * g2 + 1] = cvtpk(p2, p3);
    }
#pragma unroll
    for (int g2 = 0; g2 < 4; ++g2) {           // chain B
      float p0 = fmaxf(__builtin_amdgcn_exp2f(sB[4 * g2 + 0]), 0.f);
      float p1 = fmaxf(__builtin_amdgcn_exp2f(sB[4 * g2 + 1]), 0.f);
      float p2 = fmaxf(__builtin_amdgcn_exp2f(sB[4 * g2 + 2]), 0.f);
      float p3 = fmaxf(__builtin_amdgcn_exp2f(sB[4 * g2 + 3]), 0.f);
      sB0 += p0 + p2; sB1 += p1 + p3;
      pkB[2 * g2] = cvtpk(p0, p1);
      pkB[2 * g2 + 1] = cvtpk(p2, p3);
    }
#pragma unroll
    for (int s2 = 0; s2 < 2; ++s2) {
      s16x8 vf = *(const s16x8*)(vb + nt * 32 + s2 * 16 + hl * 8);  // shared
      {
        unsigned a0 = pkA[4 * s2 + 0], b0 = pkA[4 * s2 + 2];
        unsigned a1 = pkA[4 * s2 + 1], b1 = pkA[4 * s2 + 3];
        asm("v_permlane32_swap_b32 %0, %1" : "+v"(a0), "+v"(b0));
        asm("v_permlane32_swap_b32 %0, %1" : "+v"(a1), "+v"(b1));
        u32x4 fw; fw[0] = a0; fw[1] = a1; fw[2] = b0; fw[3] = b1;
        s16x8 fr = __builtin_bit_cast(s16x8, fw);
        oA = __builtin_amdgcn_mfma_f32_32x32x16_bf16(fr, vf, oA, 0, 0, 0);
      }
      {
        unsigned a0 = pkB[4 * s2 + 0], b0 = pkB[4 * s2 + 2];
        unsigned a1 = pkB[4 * s2 + 1], b1 = pkB[4 * s2 + 3];
        asm("v_permlane32_swap_b32 %0, %1" : "+v"(a0), "+v"(b0));
        asm("v_permlane32_swap_b32 %0, %1" : "+v"(a1), "+v"(b1));
        u32x4 fw; fw[0] = a0; fw[1] = a1; fw[2] = b0; fw[3] = b1;
        s16x8 fr = __builtin_bit_cast(s16x8, fw);
        oB = __builtin_amdgcn_mfma_f32_32x32x16_bf16(fr, vf, oB, 0, 0, 0);
      }
    }
  }
  float sumA = sA0 + sA1;
  sumA += __shfl_xor(sumA, 32);
  float sumB = sB0 + sB1;
  sumB += __shfl_xor(sumB, 32);
  Sums[w][0][r] = sumA;
  Sums[w][1][r] = sumB;
  if (r < 16) {
#pragma unroll
    for (int reg = 0; reg < 16; ++reg) {
      int qlocal = (reg & 3) + 8 * (reg >> 2) + 4 * hl;
      float invA = __builtin_amdgcn_rcpf(Sums[w][0][qlocal]);
      float invB = __builtin_amdgcn_rcpf(Sums[w][1][qlocal]);
      ag[((size_t)bn * TT + mtA * 32 + qlocal) * CC + h * 16 + r] = f2bf(oA[reg] * invA);
      ag[((size_t)bn * TT + mtB * 32 + qlocal) * CC + h * 16 + r] = f2bf(oB[reg] * invB);
    }
  }
}

// ---------------------------------------------------------------------------
// Kernel 3: final linear out = attn @ Wf^T + bf (fp32 out).
// Grid 512 (64-row tiles), 1 job/wave (r11 version, proven).
// ---------------------------------------------------------------------------
__global__ __launch_bounds__(256) void k_out(const short* __restrict__ ag,
                                             const short* __restrict__ wfb,
                                             const float* __restrict__ bfv,
                                             float* __restrict__ out) {
  __shared__ __align__(16) short la[64 * 64];
  const int tid = threadIdx.x;
  const int bn = blockIdx.x >> 3, t8 = blockIdx.x & 7;
  const int t0 = t8 * 64;
  for (int s = tid; s < 64 * 8; s += 256) {
    int row = s >> 3, c8 = s & 7;
    s16x8 v = *(const s16x8*)(ag + ((size_t)bn * TT + t0 + row) * 64 + c8 * 8);
    int byte = row * 128 + ((c8 * 16) ^ ((row & 7) << 4));
    *(s16x8*)((char*)la + byte) = v;
  }
  __syncthreads();
  const int lane = tid & 63, w = tid >> 6;
  const int r = lane & 31, hl = lane >> 5;
  {
    int mt = w >> 1, nt = w & 1;
    f32x16 acc;
#pragma unroll
    for (int i = 0; i < 16; ++i) acc[i] = 0.f;
#pragma unroll
    for (int c4 = 0; c4 < 4; ++c4) {
      int lrow = mt * 32 + r;
      int abyte = lrow * 128 + (((c4 * 16 + hl * 8) * 2) ^ ((lrow & 7) << 4));
      s16x8 af = *(const s16x8*)((const char*)la + abyte);
      s16x8 bfr = *(const s16x8*)(wfb + (nt * 32 + r) * 64 + c4 * 16 + hl * 8);
      acc = __builtin_amdgcn_mfma_f32_32x32x16_bf16(af, bfr, acc, 0, 0, 0);
    }
    int co = nt * 32 + r;
    float bias = bfv[co];
#pragma unroll
    for (int reg = 0; reg < 16; ++reg) {
      int trow = mt * 32 + (reg & 3) + 8 * (reg >> 2) + 4 * hl;
      out[((size_t)bn * TT + t0 + trow) * 64 + co] = acc[reg] + bias;
    }
  }
}

// ---------------------------------------------------------------------------
extern "C" void kernel_launch(void* const* d_in, const int* in_sizes, int n_in,
                              void* d_out, int out_size, void* d_ws, size_t ws_size,
                              hipStream_t stream) {
  const float* values = (const float*)d_in[0];
  const float* keys = (const float*)d_in[1];
  const float* query = (const float*)d_in[2];
  const float* Wq = (const float*)d_in[3];
  const float* bq = (const float*)d_in[4];
  const float* Wk = (const float*)d_in[5];
  const float* bk = (const float*)d_in[6];
  const float* Wv = (const float*)d_in[7];
  const float* Wf = (const float*)d_in[8];
  const float* bfv = (const float*)d_in[9];
  float* out = (float*)d_out;

  char* ws = (char*)d_ws;
  short* wsw = (short*)ws;                              // 64 KiB weights
  short* qg = (short*)(ws + (1 << 16));                 // 4 MiB each
  short* kg = (short*)(ws + (1 << 16) + (1 << 22));
  short* vgT = (short*)(ws + (1 << 16) + 2 * (1 << 22));
  short* ag = (short*)(ws + (1 << 16) + 3 * (size_t)(1 << 22));

  hipLaunchKernelGGL(k_prep, dim3(128), dim3(256), 0, stream, Wq, Wk, Wv, Wf, wsw);
  hipLaunchKernelGGL(k_qkv, dim3(1536), dim3(256), 0, stream,
                     values, keys, query, bq, bk, wsw, qg, kg, vgT);
  hipLaunchKernelGGL(k_attn, dim3(512), dim3(256), 0, stream, qg, kg, vgT, ag);
  hipLaunchKernelGGL(k_out, dim3(512), dim3(256), 0, stream, ag, wsw + 28672, bfv, out);
}

// Round 16
// 45.380 us; speedup vs baseline: 4.4835x; 1.0735x over previous
//
#include <hip/hip_runtime.h>

#define DEVI __device__ __forceinline__

typedef __attribute__((ext_vector_type(8)))  short s16x8;
typedef __attribute__((ext_vector_type(4)))  short s16x4;
typedef __attribute__((ext_vector_type(4)))  float f32x4;
typedef __attribute__((ext_vector_type(16))) float f32x16;
typedef __attribute__((ext_vector_type(2)))  unsigned u32x2;
typedef __attribute__((ext_vector_type(4)))  unsigned u32x4;

// float -> bf16 (RNE), bit pattern as short
DEVI short f2bf(float f) {
  unsigned u = __builtin_bit_cast(unsigned, f);
  u = u + 0x7fffu + ((u >> 16) & 1u);
  return (short)(u >> 16);
}
// two floats -> packed bf16 pair via HW cvt (RNE)
DEVI unsigned cvtpk(float lo, float hi) {
  unsigned r;
  asm("v_cvt_pk_bf16_f32 %0, %1, %2" : "=v"(r) : "v"(lo), "v"(hi));
  return r;
}

constexpr int TT = 512;
constexpr int CC = 64;
constexpr float SCLQ = 0.18033688011112042f;  // log2(e)/8, folded into Q

// ---------------------------------------------------------------------------
// Kernel 0: weight repack fp32 -> bf16.  WqB[kk][co][ci] = Wq[co][ci][kk]
// ---------------------------------------------------------------------------
__global__ __launch_bounds__(256) void k_prep(const float* __restrict__ Wq,
                                              const float* __restrict__ Wk,
                                              const float* __restrict__ Wv,
                                              const float* __restrict__ Wf,
                                              short* __restrict__ wsw) {
  int i = blockIdx.x * 256 + threadIdx.x;
  const int total = 12288 + 12288 + 4096 + 4096;
  if (i >= total) return;
  if (i < 12288) {
    int kk = i >> 12, rem = i & 4095;
    wsw[(kk << 12) + rem] = f2bf(Wq[rem * 3 + kk]);
  } else if (i < 24576) {
    int j = i - 12288;
    int kk = j >> 12, rem = j & 4095;
    wsw[12288 + (kk << 12) + rem] = f2bf(Wk[rem * 3 + kk]);
  } else if (i < 28672) {
    int j = i - 24576;
    wsw[24576 + j] = f2bf(Wv[j]);
  } else {
    int j = i - 28672;
    wsw[28672 + j] = f2bf(Wf[j]);
  }
}

// ---------------------------------------------------------------------------
// Kernel 1: QKV projections (r11 occupancy-fixed version, proven).
// Grid 1536 = tensor(3) x bn(64) x t-tile(8 of 64 rows).
// ---------------------------------------------------------------------------
__global__ __launch_bounds__(256) void k_qkv(const float* __restrict__ values,
                                             const float* __restrict__ keys,
                                             const float* __restrict__ query,
                                             const float* __restrict__ bq,
                                             const float* __restrict__ bk,
                                             const short* __restrict__ wsw,
                                             short* __restrict__ qg,
                                             short* __restrict__ kg,
                                             short* __restrict__ vgT) {
  __shared__ __align__(16) short lx[66 * 64];   // input tile (66 rows w/ halo)
  __shared__ __align__(16) short lxT[64 * 64];  // V transpose tile [co][t]
  const int idx = blockIdx.x;
  const int tsr = idx >> 9;                 // 0=Q 1=K 2=V
  const int sub = idx & 511;
  const int bn = sub >> 3, t8 = sub & 7;
  const int t0 = t8 * 64;
  const size_t xbase = (size_t)bn * TT * CC;
  const int tid = threadIdx.x;
  const int lane = tid & 63, w = tid >> 6;
  const int r = lane & 31, hl = lane >> 5;

  const float* in = (tsr == 0) ? query : (tsr == 1) ? keys : values;
  const int nrows = (tsr < 2) ? 66 : 64;
  const int halo = (tsr < 2) ? 2 : 0;

  // stage input rows [t0-halo, t0+64) as bf16, XOR-swizzled 128B rows
  for (int s = tid; s < nrows * 8; s += 256) {
    int row = s >> 3, c8 = s & 7;
    int t = t0 - halo + row;
    u32x4 rv;
    if (t >= 0) {
      const float4 a = *(const float4*)(in + xbase + (size_t)t * 64 + c8 * 8);
      const float4 b = *(const float4*)(in + xbase + (size_t)t * 64 + c8 * 8 + 4);
      rv[0] = cvtpk(a.x, a.y); rv[1] = cvtpk(a.z, a.w);
      rv[2] = cvtpk(b.x, b.y); rv[3] = cvtpk(b.z, b.w);
    } else {
      rv = (u32x4)(0u);
    }
    int byte = row * 128 + ((c8 * 16) ^ ((row & 7) << 4));
    *(u32x4*)((char*)lx + byte) = rv;
  }
  __syncthreads();

  // 4 jobs: mt(2) x nt(2); wave w takes job w
  {
    int mt = w >> 1, nt = w & 1;
    f32x16 acc;
#pragma unroll
    for (int i = 0; i < 16; ++i) acc[i] = 0.f;

    if (tsr < 2) {
      const short* wb = tsr ? (wsw + 12288) : wsw;   // [3][64][64]
#pragma unroll
      for (int kk = 0; kk < 3; ++kk) {
#pragma unroll
        for (int c4 = 0; c4 < 4; ++c4) {
          int lrow = mt * 32 + r + kk;
          int abyte = lrow * 128 + (((c4 * 16 + hl * 8) * 2) ^ ((lrow & 7) << 4));
          s16x8 af = *(const s16x8*)((const char*)lx + abyte);
          s16x8 bfr = *(const s16x8*)(wb + kk * 4096 + (nt * 32 + r) * 64 + c4 * 16 + hl * 8);
          acc = __builtin_amdgcn_mfma_f32_32x32x16_bf16(af, bfr, acc, 0, 0, 0);
        }
      }
    } else {
      const short* wvb = wsw + 24576;                // [64][64]
#pragma unroll
      for (int c4 = 0; c4 < 4; ++c4) {
        int lrow = mt * 32 + r;
        int abyte = lrow * 128 + (((c4 * 16 + hl * 8) * 2) ^ ((lrow & 7) << 4));
        s16x8 af = *(const s16x8*)((const char*)lx + abyte);
        s16x8 bfr = *(const s16x8*)(wvb + (nt * 32 + r) * 64 + c4 * 16 + hl * 8);
        acc = __builtin_amdgcn_mfma_f32_32x32x16_bf16(af, bfr, acc, 0, 0, 0);
      }
    }
    int co = nt * 32 + r;
    if (tsr == 2) {
      // write transposed to LDS: lxT[co][t_local], XOR-swizzled 4-chunks
#pragma unroll
      for (int g2 = 0; g2 < 4; ++g2) {
        int tl = mt * 32 + g2 * 8 + hl * 4;
        u32x2 pk;
        pk[0] = cvtpk(acc[g2 * 4 + 0], acc[g2 * 4 + 1]);
        pk[1] = cvtpk(acc[g2 * 4 + 2], acc[g2 * 4 + 3]);
        *(u32x2*)(lxT + co * 64 + (tl ^ ((co & 15) << 2))) = pk;
      }
    } else {
      float bias = tsr ? bk[co] : bq[co];
      float scl = tsr ? 1.f : SCLQ;
      short* dst = tsr ? kg : qg;
#pragma unroll
      for (int reg = 0; reg < 16; ++reg) {
        int trow = mt * 32 + (reg & 3) + 8 * (reg >> 2) + 4 * hl;
        dst[((size_t)bn * TT + (t0 + trow)) * 64 + co] = f2bf((acc[reg] + bias) * scl);
      }
    }
  }
  if (tsr == 2) {
    __syncthreads();
    // coalesced copy-out: vgT[bn][co][t0 + t], 1024 chunks of 4 shorts
#pragma unroll
    for (int i = 0; i < 4; ++i) {
      int chunk = tid + 256 * i;
      int co = chunk >> 4, tc = chunk & 15;
      s16x4 v4 = *(const s16x4*)(lxT + co * 64 + ((tc * 4) ^ ((co & 15) << 2)));
      *(s16x4*)(vgT + ((size_t)bn * 64 + co) * TT + t0 + tc * 4) = v4;
    }
  }
}

// ---------------------------------------------------------------------------
// Kernel 2: attention — r14 4-wave body + V STAGED IN LDS.
// Component model (r4: graph gap ~0; r11: non-attn 18.6us; dilated warm rep
// 17.5us vs undilated 30us): the 12us delta is cold-L2 latency on the 32
// serial per-wave vf global loads (data lives in L3 after k_qkv's flush).
// Fix: bulk-stage the 16KB V slice into LDS at BW (coalesced, many
// outstanding), read vf from LDS (XOR-swizzled: 32 distinct 16B granules
// per access = 4-cycle minimum).  LDS 33KB -> still 4 blocks/CU.
// Grid 1024 = (bn,h,qq); 4 waves, 1 mt/wave (max TLP variant).
// ---------------------------------------------------------------------------
__global__ __launch_bounds__(256, 4) void k_attn(const short* __restrict__ qg,
                                                 const short* __restrict__ kg,
                                                 const short* __restrict__ vgT,
                                                 short* __restrict__ ag) {
  __shared__ __align__(16) short Kl[512 * 16];   // frag-major: tile nt at nt*512, lane*8
  __shared__ __align__(16) short Vl[16 * 512];   // [ch][t], 16B-granule XOR swizzle
  __shared__ float Sums[4][32];
  const int tid = threadIdx.x;
  // bijective XCD swizzle: all 16 (h,qq) blocks of one bn land on one XCD
  const int b = (blockIdx.x & 7) * 128 + (blockIdx.x >> 3);
  const int bn = b >> 4, h = (b >> 2) & 3, qq = b & 3;
  const int lane = tid & 63, w = tid >> 6;
  const int r = lane & 31, hl = lane >> 5;

  // stage K slice (512 x 16) into fragment-major LDS
  const short* kslice = kg + (size_t)bn * TT * CC + h * 16;
  for (int s = tid; s < 1024; s += 256) {
    int row = s >> 1, hh = s & 1;
    s16x8 kv = *(const s16x8*)(kslice + (size_t)row * CC + hh * 8);
    *(s16x8*)(Kl + (row >> 5) * 512 + (row & 31) * 8 + hh * 256) = kv;
  }
  // stage V slice (16 ch x 512 t) into LDS, 16B-granule XOR swizzle
  const short* vslice = vgT + ((size_t)bn * 64 + h * 16) * TT;
  for (int s = tid; s < 1024; s += 256) {
    int ch = s >> 6, tc = s & 63;                 // 64 granules of 16B per ch
    s16x8 vv = *(const s16x8*)(vslice + (size_t)ch * TT + tc * 8);
    *(s16x8*)((char*)Vl + ch * 1024 + ((tc * 16) ^ ((ch & 7) << 4))) = vv;
  }

  const int mt = qq * 4 + w;
  s16x8 qf = *(const s16x8*)(qg + ((size_t)bn * TT + mt * 32 + r) * CC + h * 16 + hl * 8);
  const int vch = r & 15;                         // lane's V channel (dups broadcast)
  const char* vrow = (const char*)Vl + vch * 1024;

  __syncthreads();

  f32x16 z;
#pragma unroll
  for (int i = 0; i < 16; ++i) z[i] = 0.f;
  float sm0 = 0.f, sm1 = 0.f, sm2 = 0.f, sm3 = 0.f;
  f32x16 o;
#pragma unroll
  for (int i = 0; i < 16; ++i) o[i] = 0.f;

#pragma unroll
  for (int nt = 0; nt < 16; ++nt) {
    s16x8 kf = *(const s16x8*)(Kl + nt * 512 + lane * 8);
    f32x16 s = __builtin_amdgcn_mfma_f32_32x32x16_bf16(kf, qf, z, 0, 0, 0);
    float p[16];
#pragma unroll
    for (int i = 0; i < 16; ++i)
      p[i] = fmaxf(__builtin_amdgcn_exp2f(s[i]), 0.f);  // v_max shields asm consumer
#pragma unroll
    for (int i = 0; i < 4; ++i) {
      sm0 += p[4 * i + 0]; sm1 += p[4 * i + 1];
      sm2 += p[4 * i + 2]; sm3 += p[4 * i + 3];
    }
    unsigned pk[8];
#pragma unroll
    for (int m = 0; m < 8; ++m) pk[m] = cvtpk(p[2 * m], p[2 * m + 1]);
#pragma unroll
    for (int s2 = 0; s2 < 2; ++s2) {
      unsigned a0 = pk[4 * s2 + 0], b0 = pk[4 * s2 + 2];
      unsigned a1 = pk[4 * s2 + 1], b1 = pk[4 * s2 + 3];
      asm("v_permlane32_swap_b32 %0, %1" : "+v"(a0), "+v"(b0));
      asm("v_permlane32_swap_b32 %0, %1" : "+v"(a1), "+v"(b1));
      u32x4 fw; fw[0] = a0; fw[1] = a1; fw[2] = b0; fw[3] = b1;
      s16x8 fr = __builtin_bit_cast(s16x8, fw);
      s16x8 vf = *(const s16x8*)(vrow + (((nt * 32 + s2 * 16 + hl * 8) * 2) ^ ((vch & 7) << 4)));
      o = __builtin_amdgcn_mfma_f32_32x32x16_bf16(fr, vf, o, 0, 0, 0);
    }
  }
  float sum = (sm0 + sm1) + (sm2 + sm3);
  sum += __shfl_xor(sum, 32);
  Sums[w][r] = sum;
  if (r < 16) {
#pragma unroll
    for (int reg = 0; reg < 16; ++reg) {
      int qlocal = (reg & 3) + 8 * (reg >> 2) + 4 * hl;
      float inv = __builtin_amdgcn_rcpf(Sums[w][qlocal]);
      int q = mt * 32 + qlocal;
      ag[((size_t)bn * TT + q) * CC + h * 16 + r] = f2bf(o[reg] * inv);
    }
  }
}

// ---------------------------------------------------------------------------
// Kernel 3: final linear out = attn @ Wf^T + bf (fp32 out).
// Grid 512 (64-row tiles), 1 job/wave (r11 version, proven).
// ---------------------------------------------------------------------------
__global__ __launch_bounds__(256) void k_out(const short* __restrict__ ag,
                                             const short* __restrict__ wfb,
                                             const float* __restrict__ bfv,
                                             float* __restrict__ out) {
  __shared__ __align__(16) short la[64 * 64];
  const int tid = threadIdx.x;
  const int bn = blockIdx.x >> 3, t8 = blockIdx.x & 7;
  const int t0 = t8 * 64;
  for (int s = tid; s < 64 * 8; s += 256) {
    int row = s >> 3, c8 = s & 7;
    s16x8 v = *(const s16x8*)(ag + ((size_t)bn * TT + t0 + row) * 64 + c8 * 8);
    int byte = row * 128 + ((c8 * 16) ^ ((row & 7) << 4));
    *(s16x8*)((char*)la + byte) = v;
  }
  __syncthreads();
  const int lane = tid & 63, w = tid >> 6;
  const int r = lane & 31, hl = lane >> 5;
  {
    int mt = w >> 1, nt = w & 1;
    f32x16 acc;
#pragma unroll
    for (int i = 0; i < 16; ++i) acc[i] = 0.f;
#pragma unroll
    for (int c4 = 0; c4 < 4; ++c4) {
      int lrow = mt * 32 + r;
      int abyte = lrow * 128 + (((c4 * 16 + hl * 8) * 2) ^ ((lrow & 7) << 4));
      s16x8 af = *(const s16x8*)((const char*)la + abyte);
      s16x8 bfr = *(const s16x8*)(wfb + (nt * 32 + r) * 64 + c4 * 16 + hl * 8);
      acc = __builtin_amdgcn_mfma_f32_32x32x16_bf16(af, bfr, acc, 0, 0, 0);
    }
    int co = nt * 32 + r;
    float bias = bfv[co];
#pragma unroll
    for (int reg = 0; reg < 16; ++reg) {
      int trow = mt * 32 + (reg & 3) + 8 * (reg >> 2) + 4 * hl;
      out[((size_t)bn * TT + t0 + trow) * 64 + co] = acc[reg] + bias;
    }
  }
}

// ---------------------------------------------------------------------------
extern "C" void kernel_launch(void* const* d_in, const int* in_sizes, int n_in,
                              void* d_out, int out_size, void* d_ws, size_t ws_size,
                              hipStream_t stream) {
  const float* values = (const float*)d_in[0];
  const float* keys = (const float*)d_in[1];
  const float* query = (const float*)d_in[2];
  const float* Wq = (const float*)d_in[3];
  const float* bq = (const float*)d_in[4];
  const float* Wk = (const float*)d_in[5];
  const float* bk = (const float*)d_in[6];
  const float* Wv = (const float*)d_in[7];
  const float* Wf = (const float*)d_in[8];
  const float* bfv = (const float*)d_in[9];
  float* out = (float*)d_out;

  char* ws = (char*)d_ws;
  short* wsw = (short*)ws;                              // 64 KiB weights
  short* qg = (short*)(ws + (1 << 16));                 // 4 MiB each
  short* kg = (short*)(ws + (1 << 16) + (1 << 22));
  short* vgT = (short*)(ws + (1 << 16) + 2 * (1 << 22));
  short* ag = (short*)(ws + (1 << 16) + 3 * (size_t)(1 << 22));

  hipLaunchKernelGGL(k_prep, dim3(128), dim3(256), 0, stream, Wq, Wk, Wv, Wf, wsw);
  hipLaunchKernelGGL(k_qkv, dim3(1536), dim3(256), 0, stream,
                     values, keys, query, bq, bk, wsw, qg, kg, vgT);
  hipLaunchKernelGGL(k_attn, dim3(1024), dim3(256), 0, stream, qg, kg, vgT, ag);
  hipLaunchKernelGGL(k_out, dim3(512), dim3(256), 0, stream, ag, wsw + 28672, bfv, out);
}

// Round 17
// 44.818 us; speedup vs baseline: 4.5397x; 1.0125x over previous
//
#include <hip/hip_runtime.h>

#define DEVI __device__ __forceinline__

typedef __attribute__((ext_vector_type(8)))  short s16x8;
typedef __attribute__((ext_vector_type(4)))  short s16x4;
typedef __attribute__((ext_vector_type(4)))  float f32x4;
typedef __attribute__((ext_vector_type(16))) float f32x16;
typedef __attribute__((ext_vector_type(2)))  unsigned u32x2;
typedef __attribute__((ext_vector_type(4)))  unsigned u32x4;

// float -> bf16 (RNE), bit pattern as short
DEVI short f2bf(float f) {
  unsigned u = __builtin_bit_cast(unsigned, f);
  u = u + 0x7fffu + ((u >> 16) & 1u);
  return (short)(u >> 16);
}
// two floats -> packed bf16 pair via HW cvt (RNE)
DEVI unsigned cvtpk(float lo, float hi) {
  unsigned r;
  asm("v_cvt_pk_bf16_f32 %0, %1, %2" : "=v"(r) : "v"(lo), "v"(hi));
  return r;
}

constexpr int TT = 512;
constexpr int CC = 64;
constexpr float SCLQ = 0.18033688011112042f;  // log2(e)/8, folded into Q

// ---------------------------------------------------------------------------
// Kernel 0: weight repack fp32 -> bf16.  WqB[kk][co][ci] = Wq[co][ci][kk]
// ---------------------------------------------------------------------------
__global__ __launch_bounds__(256) void k_prep(const float* __restrict__ Wq,
                                              const float* __restrict__ Wk,
                                              const float* __restrict__ Wv,
                                              const float* __restrict__ Wf,
                                              short* __restrict__ wsw) {
  int i = blockIdx.x * 256 + threadIdx.x;
  const int total = 12288 + 12288 + 4096 + 4096;
  if (i >= total) return;
  if (i < 12288) {
    int kk = i >> 12, rem = i & 4095;
    wsw[(kk << 12) + rem] = f2bf(Wq[rem * 3 + kk]);
  } else if (i < 24576) {
    int j = i - 12288;
    int kk = j >> 12, rem = j & 4095;
    wsw[12288 + (kk << 12) + rem] = f2bf(Wk[rem * 3 + kk]);
  } else if (i < 28672) {
    int j = i - 24576;
    wsw[24576 + j] = f2bf(Wv[j]);
  } else {
    int j = i - 28672;
    wsw[28672 + j] = f2bf(Wf[j]);
  }
}

// ---------------------------------------------------------------------------
// Kernel 1: QKV projections (r11 body) + XCD-AFFINITY block decode:
// all work for batch bn lands on XCD bn>>3, matching k_attn's consumer
// placement -> qg/kg/vgT stay resident in the consuming XCD's L2.
// idx = xcd + 8*(tsr*64 + (bn&7)*8 + t8), grid 1536.
// ---------------------------------------------------------------------------
__global__ __launch_bounds__(256) void k_qkv(const float* __restrict__ values,
                                             const float* __restrict__ keys,
                                             const float* __restrict__ query,
                                             const float* __restrict__ bq,
                                             const float* __restrict__ bk,
                                             const short* __restrict__ wsw,
                                             short* __restrict__ qg,
                                             short* __restrict__ kg,
                                             short* __restrict__ vgT) {
  __shared__ __align__(16) short lx[66 * 64];   // input tile (66 rows w/ halo)
  __shared__ __align__(16) short lxT[64 * 64];  // V transpose tile [co][t]
  const int idx = blockIdx.x;
  const int xcd = idx & 7, rest = idx >> 3;     // affinity decode
  const int tsr = rest >> 6;                    // 0=Q 1=K 2=V
  const int rr = rest & 63;
  const int bn = xcd * 8 + (rr >> 3), t8 = rr & 7;
  const int t0 = t8 * 64;
  const size_t xbase = (size_t)bn * TT * CC;
  const int tid = threadIdx.x;
  const int lane = tid & 63, w = tid >> 6;
  const int r = lane & 31, hl = lane >> 5;

  const float* in = (tsr == 0) ? query : (tsr == 1) ? keys : values;
  const int nrows = (tsr < 2) ? 66 : 64;
  const int halo = (tsr < 2) ? 2 : 0;

  // stage input rows [t0-halo, t0+64) as bf16, XOR-swizzled 128B rows
  for (int s = tid; s < nrows * 8; s += 256) {
    int row = s >> 3, c8 = s & 7;
    int t = t0 - halo + row;
    u32x4 rv;
    if (t >= 0) {
      const float4 a = *(const float4*)(in + xbase + (size_t)t * 64 + c8 * 8);
      const float4 b = *(const float4*)(in + xbase + (size_t)t * 64 + c8 * 8 + 4);
      rv[0] = cvtpk(a.x, a.y); rv[1] = cvtpk(a.z, a.w);
      rv[2] = cvtpk(b.x, b.y); rv[3] = cvtpk(b.z, b.w);
    } else {
      rv = (u32x4)(0u);
    }
    int byte = row * 128 + ((c8 * 16) ^ ((row & 7) << 4));
    *(u32x4*)((char*)lx + byte) = rv;
  }
  __syncthreads();

  // 4 jobs: mt(2) x nt(2); wave w takes job w
  {
    int mt = w >> 1, nt = w & 1;
    f32x16 acc;
#pragma unroll
    for (int i = 0; i < 16; ++i) acc[i] = 0.f;

    if (tsr < 2) {
      const short* wb = tsr ? (wsw + 12288) : wsw;   // [3][64][64]
#pragma unroll
      for (int kk = 0; kk < 3; ++kk) {
#pragma unroll
        for (int c4 = 0; c4 < 4; ++c4) {
          int lrow = mt * 32 + r + kk;
          int abyte = lrow * 128 + (((c4 * 16 + hl * 8) * 2) ^ ((lrow & 7) << 4));
          s16x8 af = *(const s16x8*)((const char*)lx + abyte);
          s16x8 bfr = *(const s16x8*)(wb + kk * 4096 + (nt * 32 + r) * 64 + c4 * 16 + hl * 8);
          acc = __builtin_amdgcn_mfma_f32_32x32x16_bf16(af, bfr, acc, 0, 0, 0);
        }
      }
    } else {
      const short* wvb = wsw + 24576;                // [64][64]
#pragma unroll
      for (int c4 = 0; c4 < 4; ++c4) {
        int lrow = mt * 32 + r;
        int abyte = lrow * 128 + (((c4 * 16 + hl * 8) * 2) ^ ((lrow & 7) << 4));
        s16x8 af = *(const s16x8*)((const char*)lx + abyte);
        s16x8 bfr = *(const s16x8*)(wvb + (nt * 32 + r) * 64 + c4 * 16 + hl * 8);
        acc = __builtin_amdgcn_mfma_f32_32x32x16_bf16(af, bfr, acc, 0, 0, 0);
      }
    }
    int co = nt * 32 + r;
    if (tsr == 2) {
      // write transposed to LDS: lxT[co][t_local], XOR-swizzled 4-chunks
#pragma unroll
      for (int g2 = 0; g2 < 4; ++g2) {
        int tl = mt * 32 + g2 * 8 + hl * 4;
        u32x2 pk;
        pk[0] = cvtpk(acc[g2 * 4 + 0], acc[g2 * 4 + 1]);
        pk[1] = cvtpk(acc[g2 * 4 + 2], acc[g2 * 4 + 3]);
        *(u32x2*)(lxT + co * 64 + (tl ^ ((co & 15) << 2))) = pk;
      }
    } else {
      float bias = tsr ? bk[co] : bq[co];
      float scl = tsr ? 1.f : SCLQ;
      short* dst = tsr ? kg : qg;
#pragma unroll
      for (int reg = 0; reg < 16; ++reg) {
        int trow = mt * 32 + (reg & 3) + 8 * (reg >> 2) + 4 * hl;
        dst[((size_t)bn * TT + (t0 + trow)) * 64 + co] = f2bf((acc[reg] + bias) * scl);
      }
    }
  }
  if (tsr == 2) {
    __syncthreads();
    // coalesced copy-out: vgT[bn][co][t0 + t], 1024 chunks of 4 shorts
#pragma unroll
    for (int i = 0; i < 4; ++i) {
      int chunk = tid + 256 * i;
      int co = chunk >> 4, tc = chunk & 15;
      s16x4 v4 = *(const s16x4*)(lxT + co * 64 + ((tc * 4) ^ ((co & 15) << 2)));
      *(s16x4*)(vgT + ((size_t)bn * 64 + co) * TT + t0 + tc * 4) = v4;
    }
  }
}

// ---------------------------------------------------------------------------
// Kernel 2: attention — r16 body (V staged in LDS), unchanged.
// Grid 1024 = (bn,h,qq); 4 waves, 1 mt/wave; bn on XCD bn>>3.
// ---------------------------------------------------------------------------
__global__ __launch_bounds__(256, 4) void k_attn(const short* __restrict__ qg,
                                                 const short* __restrict__ kg,
                                                 const short* __restrict__ vgT,
                                                 short* __restrict__ ag) {
  __shared__ __align__(16) short Kl[512 * 16];   // frag-major: tile nt at nt*512, lane*8
  __shared__ __align__(16) short Vl[16 * 512];   // [ch][t], 16B-granule XOR swizzle
  __shared__ float Sums[4][32];
  const int tid = threadIdx.x;
  // bijective XCD swizzle: all 16 (h,qq) blocks of one bn land on one XCD
  const int b = (blockIdx.x & 7) * 128 + (blockIdx.x >> 3);
  const int bn = b >> 4, h = (b >> 2) & 3, qq = b & 3;
  const int lane = tid & 63, w = tid >> 6;
  const int r = lane & 31, hl = lane >> 5;

  // stage K slice (512 x 16) into fragment-major LDS
  const short* kslice = kg + (size_t)bn * TT * CC + h * 16;
  for (int s = tid; s < 1024; s += 256) {
    int row = s >> 1, hh = s & 1;
    s16x8 kv = *(const s16x8*)(kslice + (size_t)row * CC + hh * 8);
    *(s16x8*)(Kl + (row >> 5) * 512 + (row & 31) * 8 + hh * 256) = kv;
  }
  // stage V slice (16 ch x 512 t) into LDS, 16B-granule XOR swizzle
  const short* vslice = vgT + ((size_t)bn * 64 + h * 16) * TT;
  for (int s = tid; s < 1024; s += 256) {
    int ch = s >> 6, tc = s & 63;                 // 64 granules of 16B per ch
    s16x8 vv = *(const s16x8*)(vslice + (size_t)ch * TT + tc * 8);
    *(s16x8*)((char*)Vl + ch * 1024 + ((tc * 16) ^ ((ch & 7) << 4))) = vv;
  }

  const int mt = qq * 4 + w;
  s16x8 qf = *(const s16x8*)(qg + ((size_t)bn * TT + mt * 32 + r) * CC + h * 16 + hl * 8);
  const int vch = r & 15;                         // lane's V channel (dups broadcast)
  const char* vrow = (const char*)Vl + vch * 1024;

  __syncthreads();

  f32x16 z;
#pragma unroll
  for (int i = 0; i < 16; ++i) z[i] = 0.f;
  float sm0 = 0.f, sm1 = 0.f, sm2 = 0.f, sm3 = 0.f;
  f32x16 o;
#pragma unroll
  for (int i = 0; i < 16; ++i) o[i] = 0.f;

#pragma unroll
  for (int nt = 0; nt < 16; ++nt) {
    s16x8 kf = *(const s16x8*)(Kl + nt * 512 + lane * 8);
    f32x16 s = __builtin_amdgcn_mfma_f32_32x32x16_bf16(kf, qf, z, 0, 0, 0);
    float p[16];
#pragma unroll
    for (int i = 0; i < 16; ++i)
      p[i] = fmaxf(__builtin_amdgcn_exp2f(s[i]), 0.f);  // v_max shields asm consumer
#pragma unroll
    for (int i = 0; i < 4; ++i) {
      sm0 += p[4 * i + 0]; sm1 += p[4 * i + 1];
      sm2 += p[4 * i + 2]; sm3 += p[4 * i + 3];
    }
    unsigned pk[8];
#pragma unroll
    for (int m = 0; m < 8; ++m) pk[m] = cvtpk(p[2 * m], p[2 * m + 1]);
#pragma unroll
    for (int s2 = 0; s2 < 2; ++s2) {
      unsigned a0 = pk[4 * s2 + 0], b0 = pk[4 * s2 + 2];
      unsigned a1 = pk[4 * s2 + 1], b1 = pk[4 * s2 + 3];
      asm("v_permlane32_swap_b32 %0, %1" : "+v"(a0), "+v"(b0));
      asm("v_permlane32_swap_b32 %0, %1" : "+v"(a1), "+v"(b1));
      u32x4 fw; fw[0] = a0; fw[1] = a1; fw[2] = b0; fw[3] = b1;
      s16x8 fr = __builtin_bit_cast(s16x8, fw);
      s16x8 vf = *(const s16x8*)(vrow + (((nt * 32 + s2 * 16 + hl * 8) * 2) ^ ((vch & 7) << 4)));
      o = __builtin_amdgcn_mfma_f32_32x32x16_bf16(fr, vf, o, 0, 0, 0);
    }
  }
  float sum = (sm0 + sm1) + (sm2 + sm3);
  sum += __shfl_xor(sum, 32);
  Sums[w][r] = sum;
  if (r < 16) {
#pragma unroll
    for (int reg = 0; reg < 16; ++reg) {
      int qlocal = (reg & 3) + 8 * (reg >> 2) + 4 * hl;
      float inv = __builtin_amdgcn_rcpf(Sums[w][qlocal]);
      int q = mt * 32 + qlocal;
      ag[((size_t)bn * TT + q) * CC + h * 16 + r] = f2bf(o[reg] * inv);
    }
  }
}

// ---------------------------------------------------------------------------
// Kernel 3: final linear out = attn @ Wf^T + bf (fp32 out).
// Grid 512 (64-row tiles), 1 job/wave + XCD-AFFINITY decode matching
// k_attn's ag placement: idx = xcd + 8*((bn&7)*8 + t8).
// ---------------------------------------------------------------------------
__global__ __launch_bounds__(256) void k_out(const short* __restrict__ ag,
                                             const short* __restrict__ wfb,
                                             const float* __restrict__ bfv,
                                             float* __restrict__ out) {
  __shared__ __align__(16) short la[64 * 64];
  const int tid = threadIdx.x;
  const int xcd = blockIdx.x & 7, rest = blockIdx.x >> 3;  // affinity decode
  const int bn = xcd * 8 + (rest >> 3), t8 = rest & 7;
  const int t0 = t8 * 64;
  for (int s = tid; s < 64 * 8; s += 256) {
    int row = s >> 3, c8 = s & 7;
    s16x8 v = *(const s16x8*)(ag + ((size_t)bn * TT + t0 + row) * 64 + c8 * 8);
    int byte = row * 128 + ((c8 * 16) ^ ((row & 7) << 4));
    *(s16x8*)((char*)la + byte) = v;
  }
  __syncthreads();
  const int lane = tid & 63, w = tid >> 6;
  const int r = lane & 31, hl = lane >> 5;
  {
    int mt = w >> 1, nt = w & 1;
    f32x16 acc;
#pragma unroll
    for (int i = 0; i < 16; ++i) acc[i] = 0.f;
#pragma unroll
    for (int c4 = 0; c4 < 4; ++c4) {
      int lrow = mt * 32 + r;
      int abyte = lrow * 128 + (((c4 * 16 + hl * 8) * 2) ^ ((lrow & 7) << 4));
      s16x8 af = *(const s16x8*)((const char*)la + abyte);
      s16x8 bfr = *(const s16x8*)(wfb + (nt * 32 + r) * 64 + c4 * 16 + hl * 8);
      acc = __builtin_amdgcn_mfma_f32_32x32x16_bf16(af, bfr, acc, 0, 0, 0);
    }
    int co = nt * 32 + r;
    float bias = bfv[co];
#pragma unroll
    for (int reg = 0; reg < 16; ++reg) {
      int trow = mt * 32 + (reg & 3) + 8 * (reg >> 2) + 4 * hl;
      out[((size_t)bn * TT + t0 + trow) * 64 + co] = acc[reg] + bias;
    }
  }
}

// ---------------------------------------------------------------------------
extern "C" void kernel_launch(void* const* d_in, const int* in_sizes, int n_in,
                              void* d_out, int out_size, void* d_ws, size_t ws_size,
                              hipStream_t stream) {
  const float* values = (const float*)d_in[0];
  const float* keys = (const float*)d_in[1];
  const float* query = (const float*)d_in[2];
  const float* Wq = (const float*)d_in[3];
  const float* bq = (const float*)d_in[4];
  const float* Wk = (const float*)d_in[5];
  const float* bk = (const float*)d_in[6];
  const float* Wv = (const float*)d_in[7];
  const float* Wf = (const float*)d_in[8];
  const float* bfv = (const float*)d_in[9];
  float* out = (float*)d_out;

  char* ws = (char*)d_ws;
  short* wsw = (short*)ws;                              // 64 KiB weights
  short* qg = (short*)(ws + (1 << 16));                 // 4 MiB each
  short* kg = (short*)(ws + (1 << 16) + (1 << 22));
  short* vgT = (short*)(ws + (1 << 16) + 2 * (1 << 22));
  short* ag = (short*)(ws + (1 << 16) + 3 * (size_t)(1 << 22));

  hipLaunchKernelGGL(k_prep, dim3(128), dim3(256), 0, stream, Wq, Wk, Wv, Wf, wsw);
  hipLaunchKernelGGL(k_qkv, dim3(1536), dim3(256), 0, stream,
                     values, keys, query, bq, bk, wsw, qg, kg, vgT);
  hipLaunchKernelGGL(k_attn, dim3(1024), dim3(256), 0, stream, qg, kg, vgT, ag);
  hipLaunchKernelGGL(k_out, dim3(512), dim3(256), 0, stream, ag, wsw + 28672, bfv, out);
}